// Round 1
// baseline (249.402 us; speedup 1.0000x reference)
//
#include <hip/hip_runtime.h>
#include <hip/hip_bf16.h>
#include <math.h>

// Problem constants
#define NB 2
#define NS 2048
#define ND 1024
#define NH 16
#define HD 64
#define BS (NB*NS)     // 4096 tokens
#define D3 (3*ND)      // 3072

typedef __bf16 bf16;
typedef __bf16 bf16x8 __attribute__((ext_vector_type(8)));
typedef float f32x4 __attribute__((ext_vector_type(4)));

#define MFMA16(a,b,c) __builtin_amdgcn_mfma_f32_16x16x32_bf16(a,b,c,0,0,0)

static __device__ inline f32x4 zero4() { f32x4 z; z[0]=0.f; z[1]=0.f; z[2]=0.f; z[3]=0.f; return z; }

// ---------------- f32 -> bf16 conversion (vectorized) ----------------
__global__ __launch_bounds__(256) void cvt_f32_bf16(const float* __restrict__ in,
                                                    bf16* __restrict__ out, int n8) {
    int i = blockIdx.x * 256 + threadIdx.x;
    if (i >= n8) return;
    const float4* p = (const float4*)in;
    float4 a = p[i*2], b = p[i*2+1];
    bf16x8 o;
    o[0]=(bf16)a.x; o[1]=(bf16)a.y; o[2]=(bf16)a.z; o[3]=(bf16)a.w;
    o[4]=(bf16)b.x; o[5]=(bf16)b.y; o[6]=(bf16)b.z; o[7]=(bf16)b.w;
    ((bf16x8*)out)[i] = o;
}

// ---------------- RoPE tables: cos/sin [NS][32] ----------------
__global__ __launch_bounds__(256) void rope_tab(float* __restrict__ cosT, float* __restrict__ sinT) {
    int i = blockIdx.x * 256 + threadIdx.x;    // [0, NS*32)
    int s = i >> 5, j = i & 31;
    // inv_freq = 10000^(-j/32)
    float inv = __expf(-(float)j * (9.210340372f * 0.03125f));
    float a = (float)s * inv;
    cosT[i] = cosf(a);
    sinT[i] = sinf(a);
}

// ---------------- apply RoPE in place to Q and K (bf16, head-major [bh][s][d]) ----------------
__global__ __launch_bounds__(256) void rope_apply(bf16* __restrict__ Qb, bf16* __restrict__ Kb,
                                                  const float* __restrict__ cosT,
                                                  const float* __restrict__ sinT) {
    int i = blockIdx.x * 256 + threadIdx.x;   // [0, NB*NH*NS*32)
    int row = i >> 5, j = i & 31;
    int s = row & (NS-1);
    float c  = cosT[(s<<5)+j];
    float sn = sinT[(s<<5)+j];
    size_t base = (size_t)row * HD;
    {
        float x1 = (float)Qb[base+j], x2 = (float)Qb[base+j+32];
        Qb[base+j]    = (bf16)(x1*c - x2*sn);
        Qb[base+j+32] = (bf16)(x2*c + x1*sn);
    }
    {
        float x1 = (float)Kb[base+j], x2 = (float)Kb[base+j+32];
        Kb[base+j]    = (bf16)(x1*c - x2*sn);
        Kb[base+j+32] = (bf16)(x2*c + x1*sn);
    }
}

// ---------------- GEMM: C[m,n] = sum_k A[m,k]*B[n,k], A/B bf16 K-contiguous ----------------
// EPI==0: plain f32 store to C.  EPI==1: scatter qkv into Qb/Kb/Vb head-major bf16.
template<int EPI>
__global__ __launch_bounds__(256) void gemm_bt(
    const bf16* __restrict__ A, const bf16* __restrict__ Bm,
    float* __restrict__ C, bf16* __restrict__ Qb, bf16* __restrict__ Kb, bf16* __restrict__ Vb,
    int M, int N, int K)
{
    // 128x128 tile, BK=32, 4 waves (2x2 of 64x64), 4x4 fragments each.
    __shared__ bf16 As[128][48];   // 32 used + 16 pad (96B rows, 16B aligned)
    __shared__ bf16 Bs[128][48];
    int t = threadIdx.x;
    int lane = t & 63, w = t >> 6;
    int wr = w >> 1, wc = w & 1;
    int lr = lane & 15, lg = lane >> 4;
    int m0 = blockIdx.y * 128, n0 = blockIdx.x * 128;
    int srow = t >> 2, schunk = (t & 3) * 8;

    f32x4 acc[4][4];
    for (int m=0;m<4;m++) for (int n=0;n<4;n++) acc[m][n] = zero4();

    for (int k0 = 0; k0 < K; k0 += 32) {
        *(bf16x8*)&As[srow][schunk]    = *(const bf16x8*)&A[(size_t)(m0+srow)*K + k0 + schunk];
        *(bf16x8*)&As[srow+64][schunk] = *(const bf16x8*)&A[(size_t)(m0+srow+64)*K + k0 + schunk];
        *(bf16x8*)&Bs[srow][schunk]    = *(const bf16x8*)&Bm[(size_t)(n0+srow)*K + k0 + schunk];
        *(bf16x8*)&Bs[srow+64][schunk] = *(const bf16x8*)&Bm[(size_t)(n0+srow+64)*K + k0 + schunk];
        __syncthreads();
        bf16x8 af[4], bfr[4];
        for (int m=0;m<4;m++) af[m]  = *(const bf16x8*)&As[wr*64 + m*16 + lr][lg*8];
        for (int n=0;n<4;n++) bfr[n] = *(const bf16x8*)&Bs[wc*64 + n*16 + lr][lg*8];
        for (int m=0;m<4;m++)
            for (int n=0;n<4;n++)
                acc[m][n] = MFMA16(af[m], bfr[n], acc[m][n]);
        __syncthreads();
    }

    for (int m=0;m<4;m++) for (int n=0;n<4;n++) {
        int grow = m0 + wr*64 + m*16 + lg*4;
        int gcol = n0 + wc*64 + n*16 + lr;
        for (int r=0;r<4;r++) {
            float v = acc[m][n][r];
            int gm = grow + r;
            if (EPI == 0) {
                C[(size_t)gm * N + gcol] = v;
            } else {
                int b = gm >> 11, s = gm & (NS-1);
                int which = gcol >> 10, rem = gcol & 1023;
                int h = rem >> 6, d = rem & 63;
                size_t off = ((size_t)((b*NH + h)*NS + s))*HD + d;
                bf16 bv = (bf16)v;
                if      (which == 0) Qb[off] = bv;
                else if (which == 1) Kb[off] = bv;
                else                 Vb[off] = bv;
            }
        }
    }
}

// ---------------- causal flash attention ----------------
// grid: (NS/64, NB*NH), 256 threads = 4 waves; wave w owns 16 q-rows.
__global__ __launch_bounds__(256) void attn_fwd(
    const bf16* __restrict__ Qb, const bf16* __restrict__ Kb, const bf16* __restrict__ Vb,
    bf16* __restrict__ AO)
{
    __shared__ bf16 Ks[64][72];       // K tile  [key][d]
    __shared__ bf16 Vt[64][72];       // V tile transposed [d][key]
    __shared__ bf16 Ps[4][16][72];    // per-wave P staging [q][key]
    int t = threadIdx.x;
    int lane = t & 63, w = t >> 6;
    int lr = lane & 15, lg = lane >> 4;
    int qt = blockIdx.x, bh = blockIdx.y;
    int b = bh >> 4, h = bh & 15;
    size_t base = (size_t)bh * NS * HD;
    int q0 = qt*64 + w*16;

    bf16x8 qf[2];
    for (int c=0;c<2;c++)
        qf[c] = *(const bf16x8*)&Qb[base + (size_t)(q0+lr)*HD + c*32 + lg*8];

    float m_r[4], l_r[4];
    f32x4 o_acc[4];
    for (int r=0;r<4;r++) { m_r[r] = -__builtin_inff(); l_r[r] = 0.f; }
    for (int n=0;n<4;n++) o_acc[n] = zero4();

    int sr = t >> 3, sc = (t & 7) * 8;  // stage: 32 rows x 64 cols per pass, 2 passes
    const float scale = 0.125f;

    for (int kt = 0; kt <= qt; kt++) {
        int kv0 = kt*64;
        // ---- stage K tile and V^T tile ----
        *(bf16x8*)&Ks[sr][sc]    = *(const bf16x8*)&Kb[base + (size_t)(kv0+sr)*HD + sc];
        *(bf16x8*)&Ks[sr+32][sc] = *(const bf16x8*)&Kb[base + (size_t)(kv0+sr+32)*HD + sc];
        {
            bf16x8 v0 = *(const bf16x8*)&Vb[base + (size_t)(kv0+sr)*HD + sc];
            bf16x8 v1 = *(const bf16x8*)&Vb[base + (size_t)(kv0+sr+32)*HD + sc];
            for (int i=0;i<8;i++) Vt[sc+i][sr]    = v0[i];
            for (int i=0;i<8;i++) Vt[sc+i][sr+32] = v1[i];
        }
        __syncthreads();

        // ---- S = Q K^T (16q x 64k per wave) ----
        float sv[4][4];
        for (int kb=0;kb<4;kb++) {
            f32x4 sacc = zero4();
            for (int c=0;c<2;c++) {
                bf16x8 kf = *(const bf16x8*)&Ks[kb*16 + lr][c*32 + lg*8];
                sacc = MFMA16(qf[c], kf, sacc);
            }
            for (int r=0;r<4;r++) {
                int qi = q0 + lg*4 + r;
                int ki = kv0 + kb*16 + lr;
                float v = sacc[r] * scale;
                sv[kb][r] = (ki <= qi) ? v : -__builtin_inff();
            }
        }

        // ---- online softmax (rows live on 16-lane groups) ----
        float mnew[4], f[4];
        for (int r=0;r<4;r++) {
            float tm = fmaxf(fmaxf(sv[0][r], sv[1][r]), fmaxf(sv[2][r], sv[3][r]));
            for (int off=1; off<16; off<<=1)
                tm = fmaxf(tm, __shfl_xor(tm, off));
            mnew[r] = fmaxf(m_r[r], tm);
            f[r] = __expf(m_r[r] - mnew[r]);
        }
        float p[4][4];
        for (int kb=0;kb<4;kb++)
            for (int r=0;r<4;r++)
                p[kb][r] = __expf(sv[kb][r] - mnew[r]);
        for (int r=0;r<4;r++) {
            float ps = p[0][r]+p[1][r]+p[2][r]+p[3][r];
            for (int off=1; off<16; off<<=1)
                ps += __shfl_xor(ps, off);
            l_r[r] = l_r[r]*f[r] + ps;
            m_r[r] = mnew[r];
        }
        for (int n=0;n<4;n++)
            for (int r=0;r<4;r++)
                o_acc[n][r] *= f[r];

        // ---- P -> LDS (acc layout -> A-fragment layout), per-wave region ----
        for (int kb=0;kb<4;kb++)
            for (int r=0;r<4;r++)
                Ps[w][lg*4+r][kb*16+lr] = (bf16)p[kb][r];

        // ---- O += P V ----
        for (int c=0;c<2;c++) {
            bf16x8 pf = *(const bf16x8*)&Ps[w][lr][c*32 + lg*8];
            for (int n=0;n<4;n++) {
                bf16x8 vf = *(const bf16x8*)&Vt[n*16 + lr][c*32 + lg*8];
                o_acc[n] = MFMA16(pf, vf, o_acc[n]);
            }
        }
        __syncthreads();
    }

    // ---- epilogue: normalize, write [b,s,h,d] ----
    for (int r=0;r<4;r++) {
        int q = q0 + lg*4 + r;
        float inv = 1.0f / l_r[r];
        for (int n=0;n<4;n++) {
            int d = n*16 + lr;
            AO[((size_t)(b*NS + q)*NH + h)*HD + d] = (bf16)(o_acc[n][r] * inv);
        }
    }
}

extern "C" void kernel_launch(void* const* d_in, const int* in_sizes, int n_in,
                              void* d_out, int out_size, void* d_ws, size_t ws_size,
                              hipStream_t stream) {
    const float* x     = (const float*)d_in[0];
    const float* w_in  = (const float*)d_in[1];
    const float* w_out = (const float*)d_in[2];
    float* out = (float*)d_out;

    char* p = (char*)d_ws;
    bf16* xb    = (bf16*)p; p += (size_t)BS*ND*2;          // 8 MB
    bf16* winb  = (bf16*)p; p += (size_t)D3*ND*2;          // 6 MB
    bf16* woutb = (bf16*)p; p += (size_t)ND*ND*2;          // 2 MB
    bf16* Qb    = (bf16*)p; p += (size_t)NB*NH*NS*HD*2;    // 8 MB
    bf16* Kb    = (bf16*)p; p += (size_t)NB*NH*NS*HD*2;    // 8 MB
    bf16* Vb    = (bf16*)p; p += (size_t)NB*NH*NS*HD*2;    // 8 MB
    bf16* AO    = (bf16*)p; p += (size_t)BS*ND*2;          // 8 MB
    float* cosT = (float*)p; p += (size_t)NS*32*4;
    float* sinT = (float*)p; p += (size_t)NS*32*4;

    cvt_f32_bf16<<<(BS*ND/8 + 255)/256, 256, 0, stream>>>(x, xb, BS*ND/8);
    cvt_f32_bf16<<<(D3*ND/8 + 255)/256, 256, 0, stream>>>(w_in, winb, D3*ND/8);
    cvt_f32_bf16<<<(ND*ND/8 + 255)/256, 256, 0, stream>>>(w_out, woutb, ND*ND/8);
    rope_tab<<<(NS*32)/256, 256, 0, stream>>>(cosT, sinT);

    gemm_bt<1><<<dim3(D3/128, BS/128), 256, 0, stream>>>(xb, winb, nullptr, Qb, Kb, Vb, BS, D3, ND);
    rope_apply<<<(NB*NH*NS*32)/256, 256, 0, stream>>>(Qb, Kb, cosT, sinT);
    attn_fwd<<<dim3(NS/64, NB*NH), 256, 0, stream>>>(Qb, Kb, Vb, AO);
    gemm_bt<0><<<dim3(ND/128, BS/128), 256, 0, stream>>>(AO, woutb, out, nullptr, nullptr, nullptr, BS, ND, ND);
}

// Round 2
// 156.158 us; speedup vs baseline: 1.5971x; 1.5971x over previous
//
#include <hip/hip_runtime.h>
#include <hip/hip_bf16.h>
#include <math.h>

// Problem constants
#define NB 2
#define NS 2048
#define ND 1024
#define NH 16
#define HD 64
#define BS (NB*NS)     // 4096 tokens
#define D3 (3*ND)      // 3072
#define NT (NS/64)     // 32 kv/q tiles of 64

typedef __bf16 bf16;
typedef __bf16 bf16x4 __attribute__((ext_vector_type(4)));
typedef __bf16 bf16x8 __attribute__((ext_vector_type(8)));
typedef float f32x4 __attribute__((ext_vector_type(4)));

#define MFMA16(a,b,c) __builtin_amdgcn_mfma_f32_16x16x32_bf16(a,b,c,0,0,0)

static __device__ inline f32x4 zero4() { f32x4 z; z[0]=0.f; z[1]=0.f; z[2]=0.f; z[3]=0.f; return z; }

// ---------------- f32 -> bf16 conversion (vectorized) ----------------
__global__ __launch_bounds__(256) void cvt_f32_bf16(const float* __restrict__ in,
                                                    bf16* __restrict__ out, int n8) {
    int i = blockIdx.x * 256 + threadIdx.x;
    if (i >= n8) return;
    const float4* p = (const float4*)in;
    float4 a = p[i*2], b = p[i*2+1];
    bf16x8 o;
    o[0]=(bf16)a.x; o[1]=(bf16)a.y; o[2]=(bf16)a.z; o[3]=(bf16)a.w;
    o[4]=(bf16)b.x; o[5]=(bf16)b.y; o[6]=(bf16)b.z; o[7]=(bf16)b.w;
    ((bf16x8*)out)[i] = o;
}

// ---------------- RoPE tables: cos/sin [NS][32] ----------------
__global__ __launch_bounds__(256) void rope_tab(float* __restrict__ cosT, float* __restrict__ sinT) {
    int i = blockIdx.x * 256 + threadIdx.x;    // [0, NS*32)
    int s = i >> 5, j = i & 31;
    float inv = __expf(-(float)j * (9.210340372f * 0.03125f));  // 10000^(-j/32)
    float a = (float)s * inv;
    cosT[i] = cosf(a);
    sinT[i] = sinf(a);
}

// ---------------- apply RoPE in place to Q and K; Q additionally scaled by 1/8 ----------------
__global__ __launch_bounds__(256) void rope_apply(bf16* __restrict__ Qb, bf16* __restrict__ Kb,
                                                  const float* __restrict__ cosT,
                                                  const float* __restrict__ sinT) {
    int i = blockIdx.x * 256 + threadIdx.x;   // [0, NB*NH*NS*32)
    int row = i >> 5, j = i & 31;
    int s = row & (NS-1);
    float c  = cosT[(s<<5)+j];
    float sn = sinT[(s<<5)+j];
    size_t base = (size_t)row * HD;
    {
        float x1 = (float)Qb[base+j], x2 = (float)Qb[base+j+32];
        Qb[base+j]    = (bf16)((x1*c - x2*sn) * 0.125f);   // fold softmax scale (exact pow2)
        Qb[base+j+32] = (bf16)((x2*c + x1*sn) * 0.125f);
    }
    {
        float x1 = (float)Kb[base+j], x2 = (float)Kb[base+j+32];
        Kb[base+j]    = (bf16)(x1*c - x2*sn);
        Kb[base+j+32] = (bf16)(x2*c + x1*sn);
    }
}

// ---------------- GEMM: C[m,n] = sum_k A[m,k]*B[n,k], A/B bf16 K-contiguous ----------------
// EPI==0: plain f32 store to C.  EPI==1: scatter qkv: Q/K head-major [bh][s][d], V transposed [bh][d][s].
template<int EPI>
__global__ __launch_bounds__(256) void gemm_bt(
    const bf16* __restrict__ A, const bf16* __restrict__ Bm,
    float* __restrict__ C, bf16* __restrict__ Qb, bf16* __restrict__ Kb, bf16* __restrict__ Vt,
    int M, int N, int K)
{
    __shared__ bf16 As[128][48];
    __shared__ bf16 Bs[128][48];
    int t = threadIdx.x;
    int lane = t & 63, w = t >> 6;
    int wr = w >> 1, wc = w & 1;
    int lr = lane & 15, lg = lane >> 4;
    int m0 = blockIdx.y * 128, n0 = blockIdx.x * 128;
    int srow = t >> 2, schunk = (t & 3) * 8;

    f32x4 acc[4][4];
    for (int m=0;m<4;m++) for (int n=0;n<4;n++) acc[m][n] = zero4();

    for (int k0 = 0; k0 < K; k0 += 32) {
        *(bf16x8*)&As[srow][schunk]    = *(const bf16x8*)&A[(size_t)(m0+srow)*K + k0 + schunk];
        *(bf16x8*)&As[srow+64][schunk] = *(const bf16x8*)&A[(size_t)(m0+srow+64)*K + k0 + schunk];
        *(bf16x8*)&Bs[srow][schunk]    = *(const bf16x8*)&Bm[(size_t)(n0+srow)*K + k0 + schunk];
        *(bf16x8*)&Bs[srow+64][schunk] = *(const bf16x8*)&Bm[(size_t)(n0+srow+64)*K + k0 + schunk];
        __syncthreads();
        bf16x8 af[4], bfr[4];
        for (int m=0;m<4;m++) af[m]  = *(const bf16x8*)&As[wr*64 + m*16 + lr][lg*8];
        for (int n=0;n<4;n++) bfr[n] = *(const bf16x8*)&Bs[wc*64 + n*16 + lr][lg*8];
        for (int m=0;m<4;m++)
            for (int n=0;n<4;n++)
                acc[m][n] = MFMA16(af[m], bfr[n], acc[m][n]);
        __syncthreads();
    }

    for (int m=0;m<4;m++) for (int n=0;n<4;n++) {
        int grow = m0 + wr*64 + m*16 + lg*4;
        int gcol = n0 + wc*64 + n*16 + lr;
        if (EPI == 0) {
            for (int r=0;r<4;r++)
                C[(size_t)(grow+r) * N + gcol] = acc[m][n][r];
        } else {
            int which = gcol >> 10, rem = gcol & 1023;
            int h = rem >> 6, d = rem & 63;
            if (which == 2) {
                // V^T: 4 consecutive rows (tokens) are s-contiguous -> packed 8B store
                int b = grow >> 11, s0 = grow & (NS-1);
                bf16x4 pv;
                for (int r=0;r<4;r++) pv[r] = (bf16)acc[m][n][r];
                *(bf16x4*)&Vt[((size_t)((b*NH + h)*HD + d))*NS + s0] = pv;
            } else {
                for (int r=0;r<4;r++) {
                    int gm = grow + r;
                    int b = gm >> 11, s = gm & (NS-1);
                    size_t off = ((size_t)((b*NH + h)*NS + s))*HD + d;
                    bf16 bv = (bf16)acc[m][n][r];
                    if (which == 0) Qb[off] = bv; else Kb[off] = bv;
                }
            }
        }
    }
}

// ---------------- causal flash attention, pair-balanced ----------------
// grid: (NB*NH=32, NT/2=16), 256 threads = 4 waves; block handles q-tiles {qa, NT-1-qa}.
__global__ __launch_bounds__(256) void attn_fwd(
    const bf16* __restrict__ Qb, const bf16* __restrict__ Kb, const bf16* __restrict__ Vt,
    bf16* __restrict__ AO)
{
    __shared__ bf16 Ks[2][64][72];     // [buf][key][d]
    __shared__ bf16 Vs[2][64][72];     // [buf][d][key]
    __shared__ bf16 Ps[4][16][72];     // per-wave P staging [q][key]
    int t = threadIdx.x;
    int lane = t & 63, w = t >> 6;
    int lr = lane & 15, lg = lane >> 4;
    int bh = blockIdx.x;
    int qa = blockIdx.y, qb = (NT-1) - qa;    // qa in [0,15], qb in [16,31]
    int b = bh >> 4, h = bh & 15;
    size_t base = (size_t)bh * NS * HD;

    int q0a = qa*64 + w*16, q0b = qb*64 + w*16;

    bf16x8 qfA[2], qfB[2];
    #pragma unroll
    for (int c=0;c<2;c++) {
        qfA[c] = *(const bf16x8*)&Qb[base + (size_t)(q0a+lr)*HD + c*32 + lg*8];
        qfB[c] = *(const bf16x8*)&Qb[base + (size_t)(q0b+lr)*HD + c*32 + lg*8];
    }

    float mA[4], lA[4], mB[4], lB[4];
    f32x4 oA[4], oB[4];
    #pragma unroll
    for (int r=0;r<4;r++) { mA[r]=-__builtin_inff(); lA[r]=0.f; mB[r]=-__builtin_inff(); lB[r]=0.f; }
    #pragma unroll
    for (int n=0;n<4;n++) { oA[n]=zero4(); oB[n]=zero4(); }

    int crow = t >> 3, ccol = (t & 7) * 8;    // 32 rows x 8 chunks per pass, 2 passes
    bf16x8 kr0, kr1, vr0, vr1;

    auto load_tile = [&](int kv0) {
        kr0 = *(const bf16x8*)&Kb[base + (size_t)(kv0+crow)*HD + ccol];
        kr1 = *(const bf16x8*)&Kb[base + (size_t)(kv0+crow+32)*HD + ccol];
        vr0 = *(const bf16x8*)&Vt[base + (size_t)crow*NS + kv0 + ccol];
        vr1 = *(const bf16x8*)&Vt[base + (size_t)(crow+32)*NS + kv0 + ccol];
    };
    auto store_tile = [&](int buf) {
        *(bf16x8*)&Ks[buf][crow][ccol]    = kr0;
        *(bf16x8*)&Ks[buf][crow+32][ccol] = kr1;
        *(bf16x8*)&Vs[buf][crow][ccol]    = vr0;
        *(bf16x8*)&Vs[buf][crow+32][ccol] = vr1;
    };

    auto process = [&](int buf, int kv0, int q0, bf16x8* qf,
                       float* m_r, float* l_r, f32x4* o_acc, bool diag) {
        float sv[4][4];
        __builtin_amdgcn_s_setprio(1);
        #pragma unroll
        for (int kb=0;kb<4;kb++) {
            f32x4 sacc = zero4();
            #pragma unroll
            for (int c=0;c<2;c++) {
                bf16x8 kf = *(const bf16x8*)&Ks[buf][kb*16 + lr][c*32 + lg*8];
                sacc = MFMA16(qf[c], kf, sacc);
            }
            #pragma unroll
            for (int r=0;r<4;r++) sv[kb][r] = sacc[r];
        }
        __builtin_amdgcn_s_setprio(0);
        if (diag) {
            #pragma unroll
            for (int kb=0;kb<4;kb++)
                #pragma unroll
                for (int r=0;r<4;r++) {
                    int qi = q0 + lg*4 + r, ki = kv0 + kb*16 + lr;
                    if (ki > qi) sv[kb][r] = -__builtin_inff();
                }
        }
        float mnew[4], f[4];
        #pragma unroll
        for (int r=0;r<4;r++) {
            float tm = fmaxf(fmaxf(sv[0][r], sv[1][r]), fmaxf(sv[2][r], sv[3][r]));
            #pragma unroll
            for (int off=1; off<16; off<<=1)
                tm = fmaxf(tm, __shfl_xor(tm, off));
            mnew[r] = fmaxf(m_r[r], tm);
            f[r] = __expf(m_r[r] - mnew[r]);
        }
        float p[4][4];
        #pragma unroll
        for (int kb=0;kb<4;kb++)
            #pragma unroll
            for (int r=0;r<4;r++)
                p[kb][r] = __expf(sv[kb][r] - mnew[r]);
        #pragma unroll
        for (int r=0;r<4;r++) {
            float ps = p[0][r]+p[1][r]+p[2][r]+p[3][r];
            #pragma unroll
            for (int off=1; off<16; off<<=1)
                ps += __shfl_xor(ps, off);
            l_r[r] = l_r[r]*f[r] + ps;
            m_r[r] = mnew[r];
        }
        #pragma unroll
        for (int n=0;n<4;n++)
            #pragma unroll
            for (int r=0;r<4;r++)
                o_acc[n][r] *= f[r];
        #pragma unroll
        for (int kb=0;kb<4;kb++)
            #pragma unroll
            for (int r=0;r<4;r++)
                Ps[w][lg*4+r][kb*16+lr] = (bf16)p[kb][r];
        __builtin_amdgcn_s_setprio(1);
        #pragma unroll
        for (int c=0;c<2;c++) {
            bf16x8 pf = *(const bf16x8*)&Ps[w][lr][c*32 + lg*8];
            #pragma unroll
            for (int n=0;n<4;n++) {
                bf16x8 vf = *(const bf16x8*)&Vs[buf][n*16 + lr][c*32 + lg*8];
                o_acc[n] = MFMA16(pf, vf, o_acc[n]);
            }
        }
        __builtin_amdgcn_s_setprio(0);
    };

    load_tile(0);
    store_tile(0);
    __syncthreads();

    for (int kt = 0; kt <= qb; kt++) {
        int cur = kt & 1;
        bool have_next = (kt < qb);
        if (have_next) load_tile((kt+1)*64);          // issue early (T14)
        process(cur, kt*64, q0b, qfB, mB, lB, oB, kt==qb);
        if (kt <= qa)
            process(cur, kt*64, q0a, qfA, mA, lA, oA, kt==qa);
        if (have_next) {
            store_tile(cur^1);                         // write late; vmcnt enforced by deps
            __syncthreads();                           // single barrier per kv-tile
        }
    }

    // epilogue: normalize, write [b,s,h,d]
    #pragma unroll
    for (int r=0;r<4;r++) {
        float invB = 1.0f / lB[r];
        float invA = 1.0f / lA[r];
        int qBr = q0b + lg*4 + r, qAr = q0a + lg*4 + r;
        #pragma unroll
        for (int n=0;n<4;n++) {
            int d = n*16 + lr;
            AO[((size_t)(b*NS + qBr)*NH + h)*HD + d] = (bf16)(oB[n][r] * invB);
            AO[((size_t)(b*NS + qAr)*NH + h)*HD + d] = (bf16)(oA[n][r] * invA);
        }
    }
}

extern "C" void kernel_launch(void* const* d_in, const int* in_sizes, int n_in,
                              void* d_out, int out_size, void* d_ws, size_t ws_size,
                              hipStream_t stream) {
    const float* x     = (const float*)d_in[0];
    const float* w_in  = (const float*)d_in[1];
    const float* w_out = (const float*)d_in[2];
    float* out = (float*)d_out;

    char* p = (char*)d_ws;
    bf16* xb    = (bf16*)p; p += (size_t)BS*ND*2;          // 8 MB
    bf16* winb  = (bf16*)p; p += (size_t)D3*ND*2;          // 6 MB
    bf16* woutb = (bf16*)p; p += (size_t)ND*ND*2;          // 2 MB
    bf16* Qb    = (bf16*)p; p += (size_t)NB*NH*NS*HD*2;    // 8 MB
    bf16* Kb    = (bf16*)p; p += (size_t)NB*NH*NS*HD*2;    // 8 MB
    bf16* Vtg   = (bf16*)p; p += (size_t)NB*NH*NS*HD*2;    // 8 MB  (V transposed [bh][d][s])
    bf16* AO    = (bf16*)p; p += (size_t)BS*ND*2;          // 8 MB
    float* cosT = (float*)p; p += (size_t)NS*32*4;
    float* sinT = (float*)p; p += (size_t)NS*32*4;

    cvt_f32_bf16<<<(BS*ND/8 + 255)/256, 256, 0, stream>>>(x, xb, BS*ND/8);
    cvt_f32_bf16<<<(D3*ND/8 + 255)/256, 256, 0, stream>>>(w_in, winb, D3*ND/8);
    cvt_f32_bf16<<<(ND*ND/8 + 255)/256, 256, 0, stream>>>(w_out, woutb, ND*ND/8);
    rope_tab<<<(NS*32)/256, 256, 0, stream>>>(cosT, sinT);

    gemm_bt<1><<<dim3(D3/128, BS/128), 256, 0, stream>>>(xb, winb, nullptr, Qb, Kb, Vtg, BS, D3, ND);
    rope_apply<<<(NB*NH*NS*32)/256, 256, 0, stream>>>(Qb, Kb, cosT, sinT);
    attn_fwd<<<dim3(NB*NH, NT/2), 256, 0, stream>>>(Qb, Kb, Vtg, AO);
    gemm_bt<0><<<dim3(ND/128, BS/128), 256, 0, stream>>>(AO, woutb, out, nullptr, nullptr, nullptr, BS, ND, ND);
}

// Round 3
// 138.100 us; speedup vs baseline: 1.8060x; 1.1308x over previous
//
#include <hip/hip_runtime.h>
#include <hip/hip_bf16.h>
#include <math.h>

// Problem constants
#define NB 2
#define NS 2048
#define ND 1024
#define NH 16
#define HD 64
#define BS (NB*NS)     // 4096 tokens
#define D3 (3*ND)      // 3072
#define NT (NS/64)     // 32 kv/q tiles of 64

typedef __bf16 bf16;
typedef __bf16 bf16x4 __attribute__((ext_vector_type(4)));
typedef __bf16 bf16x8 __attribute__((ext_vector_type(8)));
typedef float f32x4 __attribute__((ext_vector_type(4)));

#define MFMA16(a,b,c) __builtin_amdgcn_mfma_f32_16x16x32_bf16(a,b,c,0,0,0)

static __device__ inline f32x4 zero4() { f32x4 z; z[0]=0.f; z[1]=0.f; z[2]=0.f; z[3]=0.f; return z; }

// global -> LDS direct copy, 16B per lane; lds base must be wave-uniform.
__device__ __forceinline__ void gload_lds16(const bf16* g, bf16* l) {
    __builtin_amdgcn_global_load_lds(
        (__attribute__((address_space(1))) unsigned int*)g,
        (__attribute__((address_space(3))) unsigned int*)l, 16, 0, 0);
}

// ---------------- f32 -> bf16 conversion (vectorized) ----------------
__global__ __launch_bounds__(256) void cvt_f32_bf16(const float* __restrict__ in,
                                                    bf16* __restrict__ out, int n8) {
    int i = blockIdx.x * 256 + threadIdx.x;
    if (i >= n8) return;
    const float4* p = (const float4*)in;
    float4 a = p[i*2], b = p[i*2+1];
    bf16x8 o;
    o[0]=(bf16)a.x; o[1]=(bf16)a.y; o[2]=(bf16)a.z; o[3]=(bf16)a.w;
    o[4]=(bf16)b.x; o[5]=(bf16)b.y; o[6]=(bf16)b.z; o[7]=(bf16)b.w;
    ((bf16x8*)out)[i] = o;
}

// ---------------- RoPE tables: cos/sin [NS][32] ----------------
__global__ __launch_bounds__(256) void rope_tab(float* __restrict__ cosT, float* __restrict__ sinT) {
    int i = blockIdx.x * 256 + threadIdx.x;    // [0, NS*32)
    int s = i >> 5, j = i & 31;
    float inv = __expf(-(float)j * (9.210340372f * 0.03125f));  // 10000^(-j/32)
    float a = (float)s * inv;
    cosT[i] = cosf(a);
    sinT[i] = sinf(a);
}

// ---------------- apply RoPE in place; Q scaled by 0.125*log2(e) (log2-domain scores) ----------------
__global__ __launch_bounds__(256) void rope_apply(bf16* __restrict__ Qb, bf16* __restrict__ Kb,
                                                  const float* __restrict__ cosT,
                                                  const float* __restrict__ sinT) {
    int i = blockIdx.x * 256 + threadIdx.x;   // [0, NB*NH*NS*32)
    int row = i >> 5, j = i & 31;
    int s = row & (NS-1);
    float c  = cosT[(s<<5)+j];
    float sn = sinT[(s<<5)+j];
    size_t base = (size_t)row * HD;
    const float qs = 0.18033688f;   // 0.125 * log2(e)
    {
        float x1 = (float)Qb[base+j], x2 = (float)Qb[base+j+32];
        Qb[base+j]    = (bf16)((x1*c - x2*sn) * qs);
        Qb[base+j+32] = (bf16)((x2*c + x1*sn) * qs);
    }
    {
        float x1 = (float)Kb[base+j], x2 = (float)Kb[base+j+32];
        Kb[base+j]    = (bf16)(x1*c - x2*sn);
        Kb[base+j+32] = (bf16)(x2*c + x1*sn);
    }
}

// ---------------- GEMM: C[m,n] = sum_k A[m,k]*B[n,k], A/B bf16 K-contiguous ----------------
// global_load_lds staging (m97 structure), linear LDS [128][32].
// EPI==0: plain f32 store. EPI==1: Q/K head-major [bh][s][d]; V transposed+k-permuted [bh][d][s'].
template<int EPI>
__global__ __launch_bounds__(256) void gemm_bt(
    const bf16* __restrict__ A, const bf16* __restrict__ Bm,
    float* __restrict__ C, bf16* __restrict__ Qb, bf16* __restrict__ Kb, bf16* __restrict__ Vt,
    int M, int N, int K)
{
    __shared__ bf16 As[128*32];
    __shared__ bf16 Bs[128*32];
    int t = threadIdx.x;
    int lane = t & 63, w = t >> 6;
    int wr = w >> 1, wc = w & 1;
    int lr = lane & 15, lg = lane >> 4;
    int m0 = blockIdx.y * 128, n0 = blockIdx.x * 128;

    // staging: wave w covers rows w*32 .. w*32+31 (two 1KB chunks each of A and B)
    int srow = w*32 + (lane >> 2);
    int scol = (lane & 3) * 8;
    const bf16* gA0 = &A [(size_t)(m0+srow)*K + scol];
    const bf16* gA1 = &A [(size_t)(m0+srow+16)*K + scol];
    const bf16* gB0 = &Bm[(size_t)(n0+srow)*K + scol];
    const bf16* gB1 = &Bm[(size_t)(n0+srow+16)*K + scol];
    bf16* lA0 = &As[w*1024];
    bf16* lA1 = &As[w*1024 + 512];
    bf16* lB0 = &Bs[w*1024];
    bf16* lB1 = &Bs[w*1024 + 512];

    f32x4 acc[4][4];
    for (int m=0;m<4;m++) for (int n=0;n<4;n++) acc[m][n] = zero4();

    for (int k0 = 0; k0 < K; k0 += 32) {
        gload_lds16(gA0 + k0, lA0);
        gload_lds16(gA1 + k0, lA1);
        gload_lds16(gB0 + k0, lB0);
        gload_lds16(gB1 + k0, lB1);
        __syncthreads();
        bf16x8 af[4], bfr[4];
        #pragma unroll
        for (int m=0;m<4;m++) af[m]  = *(const bf16x8*)&As[(wr*64 + m*16 + lr)*32 + lg*8];
        #pragma unroll
        for (int n=0;n<4;n++) bfr[n] = *(const bf16x8*)&Bs[(wc*64 + n*16 + lr)*32 + lg*8];
        #pragma unroll
        for (int m=0;m<4;m++)
            #pragma unroll
            for (int n=0;n<4;n++)
                acc[m][n] = MFMA16(af[m], bfr[n], acc[m][n]);
        __syncthreads();
    }

    for (int m=0;m<4;m++) for (int n=0;n<4;n++) {
        int grow = m0 + wr*64 + m*16 + lg*4;
        int gcol = n0 + wc*64 + n*16 + lr;
        if (EPI == 0) {
            for (int r=0;r<4;r++)
                C[(size_t)(grow+r) * N + gcol] = acc[m][n][r];
        } else {
            int which = gcol >> 10, rem = gcol & 1023;
            int h = rem >> 6, d = rem & 63;
            if (which == 2) {
                // V^T with within-64 k-permutation: k' = c*32 + lg*8 + kb'*4 + r
                int b = grow >> 11, s0 = grow & (NS-1);
                int shi = s0 & ~63, j = s0 & 63;   // j % 4 == 0
                int kp = ((j>>5)&1)*32 + ((j>>2)&3)*8 + ((j>>4)&1)*4;
                bf16x4 pv;
                for (int r=0;r<4;r++) pv[r] = (bf16)acc[m][n][r];
                *(bf16x4*)&Vt[((size_t)((b*NH + h)*HD + d))*NS + shi + kp] = pv;
            } else {
                for (int r=0;r<4;r++) {
                    int gm = grow + r;
                    int b = gm >> 11, s = gm & (NS-1);
                    size_t off = ((size_t)((b*NH + h)*NS + s))*HD + d;
                    bf16 bv = (bf16)acc[m][n][r];
                    if (which == 0) Qb[off] = bv; else Kb[off] = bv;
                }
            }
        }
    }
}

// ---------------- causal flash attention, swapped QK^T, in-register softmax ----------------
// grid: (NB*NH=32, NT/2=16), 256 threads = 4 waves; block handles q-tiles {qa, NT-1-qa}.
__global__ __launch_bounds__(256, 2) void attn_fwd(
    const bf16* __restrict__ Qb, const bf16* __restrict__ Kb, const bf16* __restrict__ Vp,
    bf16* __restrict__ AO)
{
    __shared__ bf16 Ks[2][64][72];     // [buf][key][d]
    __shared__ bf16 Vs[2][64][72];     // [buf][d][k'-permuted]
    int t = threadIdx.x;
    int lane = t & 63, w = t >> 6;
    int lr = lane & 15, lg = lane >> 4;
    int bh = blockIdx.x;
    int qa = blockIdx.y, qb = (NT-1) - qa;
    int b = bh >> 4, h = bh & 15;
    size_t base = (size_t)bh * NS * HD;

    int q0a = qa*64 + w*16, q0b = qb*64 + w*16;

    // Q fragments (B-operand role: col = q = lr, k-elems = hd)
    bf16x8 qfA[2], qfB[2];
    #pragma unroll
    for (int c=0;c<2;c++) {
        qfA[c] = *(const bf16x8*)&Qb[base + (size_t)(q0a+lr)*HD + c*32 + lg*8];
        qfB[c] = *(const bf16x8*)&Qb[base + (size_t)(q0b+lr)*HD + c*32 + lg*8];
    }

    // per-lane scalars: each lane owns q = lr (replicated across lane groups)
    float mA = -__builtin_inff(), lA = 0.f;
    float mB = -__builtin_inff(), lB = 0.f;
    f32x4 oA[4], oB[4];     // O^T[d-block n][4 d][q=lr]
    #pragma unroll
    for (int n=0;n<4;n++) { oA[n]=zero4(); oB[n]=zero4(); }

    int crow = t >> 3, ccol = (t & 7) * 8;
    bf16x8 kr0, kr1, vr0, vr1;

    auto load_tile = [&](int kv0) {
        kr0 = *(const bf16x8*)&Kb[base + (size_t)(kv0+crow)*HD + ccol];
        kr1 = *(const bf16x8*)&Kb[base + (size_t)(kv0+crow+32)*HD + ccol];
        vr0 = *(const bf16x8*)&Vp[base + (size_t)crow*NS + kv0 + ccol];
        vr1 = *(const bf16x8*)&Vp[base + (size_t)(crow+32)*NS + kv0 + ccol];
    };
    auto store_tile = [&](int buf) {
        *(bf16x8*)&Ks[buf][crow][ccol]    = kr0;
        *(bf16x8*)&Ks[buf][crow+32][ccol] = kr1;
        *(bf16x8*)&Vs[buf][crow][ccol]    = vr0;
        *(bf16x8*)&Vs[buf][crow+32][ccol] = vr1;
    };

    auto process = [&](bf16x8 (&kf)[4][2], bf16x8 (&vf)[2][4], int kv0, int q0,
                       bf16x8* qf, float& m_r, float& l_r, f32x4* o, bool diag) {
        // S^T = K Q : sc[kb][r] = S[kv0+kb*16+lg*4+r][q0+lr]  (log2-domain)
        f32x4 sc[4];
        __builtin_amdgcn_s_setprio(1);
        #pragma unroll
        for (int kb=0;kb<4;kb++) {
            sc[kb] = zero4();
            #pragma unroll
            for (int c=0;c<2;c++)
                sc[kb] = MFMA16(kf[kb][c], qf[c], sc[kb]);
        }
        __builtin_amdgcn_s_setprio(0);
        int qi = q0 + lr;
        if (diag) {
            #pragma unroll
            for (int kb=0;kb<4;kb++)
                #pragma unroll
                for (int r=0;r<4;r++)
                    if (kv0 + kb*16 + lg*4 + r > qi) sc[kb][r] = -__builtin_inff();
        }
        // row max: 15 local + 2 cross-group shuffles
        float tm = fmaxf(fmaxf(sc[0][0], sc[0][1]), fmaxf(sc[0][2], sc[0][3]));
        #pragma unroll
        for (int kb=1;kb<4;kb++)
            tm = fmaxf(tm, fmaxf(fmaxf(sc[kb][0], sc[kb][1]), fmaxf(sc[kb][2], sc[kb][3])));
        tm = fmaxf(tm, __shfl_xor(tm, 16));
        tm = fmaxf(tm, __shfl_xor(tm, 32));
        float mn = fmaxf(m_r, tm);
        float fsc = exp2f(m_r - mn);
        float pv[4][4];
        float ps = 0.f;
        #pragma unroll
        for (int kb=0;kb<4;kb++)
            #pragma unroll
            for (int r=0;r<4;r++) {
                float pe = exp2f(sc[kb][r] - mn);
                pv[kb][r] = pe;
                ps += pe;
            }
        ps += __shfl_xor(ps, 16);
        ps += __shfl_xor(ps, 32);
        l_r = l_r * fsc + ps;
        m_r = mn;
        #pragma unroll
        for (int n=0;n<4;n++) o[n] *= fsc;
        // pack P to bf16 in the k-slot order matching the permuted V fragments
        bf16x8 pa[2];
        #pragma unroll
        for (int c=0;c<2;c++) {
            bf16x8 v;
            #pragma unroll
            for (int i=0;i<8;i++) v[i] = (bf16)pv[c*2 + (i>>2)][i&3];
            pa[c] = v;
        }
        __builtin_amdgcn_s_setprio(1);
        #pragma unroll
        for (int c=0;c<2;c++)
            #pragma unroll
            for (int n=0;n<4;n++)
                o[n] = MFMA16(vf[c][n], pa[c], o[n]);
        __builtin_amdgcn_s_setprio(0);
    };

    load_tile(0);
    store_tile(0);
    __syncthreads();

    for (int kt = 0; kt <= qb; kt++) {
        int cur = kt & 1;
        bool have_next = (kt < qb);
        if (have_next) load_tile((kt+1)*64);     // issue next-tile global loads early
        // hoist K/V fragments once, shared by both q-tiles
        bf16x8 kf[4][2], vf[2][4];
        #pragma unroll
        for (int kb=0;kb<4;kb++)
            #pragma unroll
            for (int c=0;c<2;c++)
                kf[kb][c] = *(const bf16x8*)&Ks[cur][kb*16 + lr][c*32 + lg*8];
        #pragma unroll
        for (int c=0;c<2;c++)
            #pragma unroll
            for (int n=0;n<4;n++)
                vf[c][n] = *(const bf16x8*)&Vs[cur][n*16 + lr][c*32 + lg*8];

        process(kf, vf, kt*64, q0b, qfB, mB, lB, oB, kt==qb);
        if (kt <= qa)
            process(kf, vf, kt*64, q0a, qfA, mA, lA, oA, kt==qa);
        if (have_next) {
            store_tile(cur^1);
            __syncthreads();
        }
    }

    // epilogue: normalize, write [b,s,h,d] as bf16x4 chunks
    float invB = 1.0f / lB;
    float invA = 1.0f / lA;
    int qB = q0b + lr, qA = q0a + lr;
    #pragma unroll
    for (int n=0;n<4;n++) {
        bf16x4 o1, o2;
        #pragma unroll
        for (int r=0;r<4;r++) {
            o1[r] = (bf16)(oB[n][r] * invB);
            o2[r] = (bf16)(oA[n][r] * invA);
        }
        *(bf16x4*)&AO[((size_t)(b*NS + qB)*NH + h)*HD + n*16 + lg*4] = o1;
        *(bf16x4*)&AO[((size_t)(b*NS + qA)*NH + h)*HD + n*16 + lg*4] = o2;
    }
}

extern "C" void kernel_launch(void* const* d_in, const int* in_sizes, int n_in,
                              void* d_out, int out_size, void* d_ws, size_t ws_size,
                              hipStream_t stream) {
    const float* x     = (const float*)d_in[0];
    const float* w_in  = (const float*)d_in[1];
    const float* w_out = (const float*)d_in[2];
    float* out = (float*)d_out;

    char* p = (char*)d_ws;
    bf16* xb    = (bf16*)p; p += (size_t)BS*ND*2;          // 8 MB
    bf16* winb  = (bf16*)p; p += (size_t)D3*ND*2;          // 6 MB
    bf16* woutb = (bf16*)p; p += (size_t)ND*ND*2;          // 2 MB
    bf16* Qb    = (bf16*)p; p += (size_t)NB*NH*NS*HD*2;    // 8 MB
    bf16* Kb    = (bf16*)p; p += (size_t)NB*NH*NS*HD*2;    // 8 MB
    bf16* Vp    = (bf16*)p; p += (size_t)NB*NH*NS*HD*2;    // 8 MB  (V^T, k-permuted, [bh][d][s'])
    bf16* AO    = (bf16*)p; p += (size_t)BS*ND*2;          // 8 MB
    float* cosT = (float*)p; p += (size_t)NS*32*4;
    float* sinT = (float*)p; p += (size_t)NS*32*4;

    cvt_f32_bf16<<<(BS*ND/8 + 255)/256, 256, 0, stream>>>(x, xb, BS*ND/8);
    cvt_f32_bf16<<<(D3*ND/8 + 255)/256, 256, 0, stream>>>(w_in, winb, D3*ND/8);
    cvt_f32_bf16<<<(ND*ND/8 + 255)/256, 256, 0, stream>>>(w_out, woutb, ND*ND/8);
    rope_tab<<<(NS*32)/256, 256, 0, stream>>>(cosT, sinT);

    gemm_bt<1><<<dim3(D3/128, BS/128), 256, 0, stream>>>(xb, winb, nullptr, Qb, Kb, Vp, BS, D3, ND);
    rope_apply<<<(NB*NH*NS*32)/256, 256, 0, stream>>>(Qb, Kb, cosT, sinT);
    attn_fwd<<<dim3(NB*NH, NT/2), 256, 0, stream>>>(Qb, Kb, Vp, AO);
    gemm_bt<0><<<dim3(ND/128, BS/128), 256, 0, stream>>>(AO, woutb, out, nullptr, nullptr, nullptr, BS, ND, ND);
}

// Round 4
// 125.910 us; speedup vs baseline: 1.9808x; 1.0968x over previous
//
#include <hip/hip_runtime.h>
#include <hip/hip_bf16.h>
#include <math.h>

// Problem constants
#define NB 2
#define NS 2048
#define ND 1024
#define NH 16
#define HD 64
#define BS (NB*NS)     // 4096 tokens
#define D3 (3*ND)      // 3072
#define NT (NS/64)     // 32 q-tiles of 64

typedef __bf16 bf16;
typedef __bf16 bf16x4 __attribute__((ext_vector_type(4)));
typedef __bf16 bf16x8 __attribute__((ext_vector_type(8)));
typedef float f32x4 __attribute__((ext_vector_type(4)));

#define MFMA16(a,b,c) __builtin_amdgcn_mfma_f32_16x16x32_bf16(a,b,c,0,0,0)

static __device__ inline f32x4 zero4() { f32x4 z; z[0]=0.f; z[1]=0.f; z[2]=0.f; z[3]=0.f; return z; }

// global -> LDS direct copy, 16B per lane; lds base must be wave-uniform.
__device__ __forceinline__ void gload_lds16(const bf16* g, bf16* l) {
    __builtin_amdgcn_global_load_lds(
        (__attribute__((address_space(1))) unsigned int*)g,
        (__attribute__((address_space(3))) unsigned int*)l, 16, 0, 0);
}

// ---------------- prep: f32->bf16 for x/w_in/w_out + RoPE tables, one launch ----------------
#define CVT1 (BS*ND/8)          // 524288
#define CVT2 (D3*ND/8)          // 393216
#define CVT3 (ND*ND/8)          // 131072
#define CVTN (CVT1+CVT2+CVT3)   // 1048576
__global__ __launch_bounds__(256) void prep(
    const float* __restrict__ x, const float* __restrict__ w_in, const float* __restrict__ w_out,
    bf16* __restrict__ xb, bf16* __restrict__ winb, bf16* __restrict__ woutb,
    float* __restrict__ cosT, float* __restrict__ sinT)
{
    int i = blockIdx.x * 256 + threadIdx.x;
    if (i < CVTN) {
        const float* in; bf16* out; int j;
        if (i < CVT1)            { in = x;     out = xb;    j = i; }
        else if (i < CVT1+CVT2)  { in = w_in;  out = winb;  j = i - CVT1; }
        else                     { in = w_out; out = woutb; j = i - CVT1 - CVT2; }
        const float4* p = (const float4*)in;
        float4 a = p[j*2], b = p[j*2+1];
        bf16x8 o;
        o[0]=(bf16)a.x; o[1]=(bf16)a.y; o[2]=(bf16)a.z; o[3]=(bf16)a.w;
        o[4]=(bf16)b.x; o[5]=(bf16)b.y; o[6]=(bf16)b.z; o[7]=(bf16)b.w;
        ((bf16x8*)out)[j] = o;
    } else {
        int k = i - CVTN;                      // [0, NS*32)
        int s = k >> 5, j = k & 31;
        float inv = __expf(-(float)j * (9.210340372f * 0.03125f));  // 10000^(-j/32)
        float ang = (float)s * inv;
        cosT[k] = cosf(ang);
        sinT[k] = sinf(ang);
    }
}

// ---------------- GEMM: C[m,n] = sum_k A[m,k]*B[n,k], bf16, BK=64, swizzled LDS ----------------
// Staging: global_load_lds (linear dest) + pre-swizzled SOURCE chunk; reads use same XOR (rule 21).
// EPI==0: f32 store. EPI==1: fused RoPE -> Q/K head-major [bh][s][d]; V^T k-permuted [bh][d][s'].
template<int EPI>
__global__ __launch_bounds__(256) void gemm_bt(
    const bf16* __restrict__ A, const bf16* __restrict__ Bm,
    float* __restrict__ C, bf16* __restrict__ Qb, bf16* __restrict__ Kb, bf16* __restrict__ Vt,
    const float* __restrict__ cosT, const float* __restrict__ sinT,
    int M, int N, int K)
{
    __shared__ bf16 As[128*64];
    __shared__ bf16 Bs[128*64];
    int t = threadIdx.x;
    int lane = t & 63, w = t >> 6;
    int wr = w >> 1, wc = w & 1;
    int lr = lane & 15, lg = lane >> 4;
    int m0 = blockIdx.y * 128, n0 = blockIdx.x * 128;

    // staging: wave w covers 32 rows of A and B; source chunk pre-swizzled by row&7
    int srow = lane >> 3;                 // 0..7
    int schunk = (lane & 7) ^ srow;       // XOR-swizzled source chunk
    const bf16* gA = &A [(size_t)(m0 + w*32 + srow)*K + schunk*8];
    const bf16* gB = &Bm[(size_t)(n0 + w*32 + srow)*K + schunk*8];
    bf16* lA = &As[w*2048];
    bf16* lB = &Bs[w*2048];

    f32x4 acc[4][4];
    for (int m=0;m<4;m++) for (int n=0;n<4;n++) acc[m][n] = zero4();

    for (int k0 = 0; k0 < K; k0 += 64) {
        #pragma unroll
        for (int i=0;i<4;i++) {
            gload_lds16(gA + (size_t)(i*8)*K + k0, lA + i*512);
            gload_lds16(gB + (size_t)(i*8)*K + k0, lB + i*512);
        }
        __syncthreads();
        #pragma unroll
        for (int ks=0;ks<2;ks++) {
            bf16x8 af[4], bfr[4];
            #pragma unroll
            for (int m=0;m<4;m++) {
                int row = wr*64 + m*16 + lr;
                af[m] = *(const bf16x8*)&As[row*64 + (((ks*4+lg) ^ (row&7))*8)];
            }
            #pragma unroll
            for (int n=0;n<4;n++) {
                int row = wc*64 + n*16 + lr;
                bfr[n] = *(const bf16x8*)&Bs[row*64 + (((ks*4+lg) ^ (row&7))*8)];
            }
            #pragma unroll
            for (int m=0;m<4;m++)
                #pragma unroll
                for (int n=0;n<4;n++)
                    acc[m][n] = MFMA16(af[m], bfr[n], acc[m][n]);
        }
        __syncthreads();
    }

    if (EPI == 0) {
        for (int m=0;m<4;m++) for (int n=0;n<4;n++) {
            int grow = m0 + wr*64 + m*16 + lg*4;
            int gcol = n0 + wc*64 + n*16 + lr;
            for (int r=0;r<4;r++)
                C[(size_t)(grow+r) * N + gcol] = acc[m][n][r];
        }
    } else {
        int which = n0 >> 10;   // block-uniform (128-col block never straddles a 1024 boundary)
        if (which == 2) {
            // V^T with within-64 k-permutation: col(t) = ((t>>5)&1)*32+((t>>2)&3)*8+((t>>4)&1)*4+(t&3)
            for (int m=0;m<4;m++) for (int n=0;n<4;n++) {
                int grow = m0 + wr*64 + m*16 + lg*4;
                int gcol = n0 + wc*64 + n*16 + lr;
                int h = (gcol & 1023) >> 6, d = gcol & 63;
                int b = grow >> 11, s0 = grow & (NS-1);
                int shi = s0 & ~63, j = s0 & 63;   // j % 4 == 0
                int kp = ((j>>5)&1)*32 + ((j>>2)&3)*8 + ((j>>4)&1)*4;
                bf16x4 pv;
                for (int r=0;r<4;r++) pv[r] = (bf16)acc[m][n][r];
                *(bf16x4*)&Vt[((size_t)((b*NH + h)*HD + d))*NS + shi + kp] = pv;
            }
        } else {
            // fused RoPE: pairs (d, d+32) = acc n and n+2, same lane
            const float qs = 0.125f * 1.44269504f;   // fold softmax scale + log2(e) into Q
            bf16* dst = (which == 0) ? Qb : Kb;
            for (int m=0;m<4;m++) {
                int grow = m0 + wr*64 + m*16 + lg*4;
                #pragma unroll
                for (int n=0;n<2;n++) {
                    int gcol = n0 + wc*64 + n*16 + lr;
                    int h = (gcol & 1023) >> 6, j = gcol & 63;   // j in [0,32)
                    #pragma unroll
                    for (int r=0;r<4;r++) {
                        int gm = grow + r;
                        int b = gm >> 11, s = gm & (NS-1);
                        float c  = cosT[(s<<5)+j];
                        float sn = sinT[(s<<5)+j];
                        float x1 = acc[m][n][r], x2 = acc[m][n+2][r];
                        float y1 = x1*c - x2*sn;
                        float y2 = x2*c + x1*sn;
                        if (which == 0) { y1 *= qs; y2 *= qs; }
                        size_t off = ((size_t)((b*NH + h)*NS + s))*HD;
                        dst[off + j]      = (bf16)y1;
                        dst[off + j + 32] = (bf16)y2;
                    }
                }
            }
        }
    }
}

// ---------------- causal flash attention: KVBLK=128, swizzled LDS, defer-max ----------------
// flat grid 512; XCD-clustered decode. Block handles q-tiles {qa, 31-qa}: 17 iters of 128 keys.
__global__ __launch_bounds__(256, 2) void attn_fwd(
    const bf16* __restrict__ Qb, const bf16* __restrict__ Kb, const bf16* __restrict__ Vp,
    bf16* __restrict__ AO)
{
    __shared__ bf16 Ks[2][128*64];     // [buf][key][d], chunk-swizzled
    __shared__ bf16 Vs[2][64*128];     // [buf][d][k'],  chunk-swizzled
    int t = threadIdx.x;
    int lane = t & 63, w = t >> 6;
    int lr = lane & 15, lg = lane >> 4;
    // XCD-clustered decode: xcd = wgid&7 gets 4 heads' 16 pair-blocks each
    int wgid = blockIdx.x;
    int xcd = wgid & 7, kk = wgid >> 3;
    int bh = xcd*4 + (kk >> 4);
    int qa = kk & 15, qb = (NT-1) - qa;
    int b = bh >> 4, h = bh & 15;
    size_t base = (size_t)bh * NS * HD;

    int q0a = qa*64 + w*16, q0b = qb*64 + w*16;

    bf16x8 qfA[2], qfB[2];
    #pragma unroll
    for (int c=0;c<2;c++) {
        qfA[c] = *(const bf16x8*)&Qb[base + (size_t)(q0a+lr)*HD + c*32 + lg*8];
        qfB[c] = *(const bf16x8*)&Qb[base + (size_t)(q0b+lr)*HD + c*32 + lg*8];
    }

    float mA = -__builtin_inff(), lsA = 0.f;
    float mB = -__builtin_inff(), lsB = 0.f;
    f32x4 oA[4], oB[4];
    #pragma unroll
    for (int n=0;n<4;n++) { oA[n]=zero4(); oB[n]=zero4(); }

    // staging addressing (reg-staged for swizzled writes)
    int krow = t >> 3;                    // 0..31
    int kch  = t & 7;
    int kslot = kch ^ (krow & 7);
    int vrow = t >> 4;                    // 0..15
    int vch  = t & 15;
    int vslot = vch ^ (vrow & 7);
    bf16x8 kr[4], vr[4];

    auto load_window = [&](int kv0) {
        #pragma unroll
        for (int i=0;i<4;i++)
            kr[i] = *(const bf16x8*)&Kb[base + (size_t)(kv0 + i*32 + krow)*HD + kch*8];
        #pragma unroll
        for (int i=0;i<4;i++)
            vr[i] = *(const bf16x8*)&Vp[base + (size_t)(i*16 + vrow)*NS + kv0 + vch*8];
    };
    auto store_window = [&](int buf) {
        #pragma unroll
        for (int i=0;i<4;i++)
            *(bf16x8*)&Ks[buf][(i*32 + krow)*64 + kslot*8] = kr[i];
        #pragma unroll
        for (int i=0;i<4;i++)
            *(bf16x8*)&Vs[buf][(i*16 + vrow)*128 + vslot*8] = vr[i];
    };

    auto softmax = [&](f32x4* sc, float& m_r, float& l_r, f32x4* o, bf16x8* pa,
                       bool diag, int kv0, int qi) {
        if (diag) {
            #pragma unroll
            for (int kb=0;kb<8;kb++)
                #pragma unroll
                for (int r=0;r<4;r++)
                    if (kv0 + kb*16 + lg*4 + r > qi) sc[kb][r] = -__builtin_inff();
        }
        float tm = fmaxf(fmaxf(sc[0][0],sc[0][1]), fmaxf(sc[0][2],sc[0][3]));
        #pragma unroll
        for (int kb=1;kb<8;kb++)
            tm = fmaxf(tm, fmaxf(fmaxf(sc[kb][0],sc[kb][1]), fmaxf(sc[kb][2],sc[kb][3])));
        tm = fmaxf(tm, __shfl_xor(tm, 16));
        tm = fmaxf(tm, __shfl_xor(tm, 32));
        if (!__all(tm <= m_r + 8.0f)) {        // defer-max: rescale only on real growth
            float mn = fmaxf(m_r, tm);
            float fsc = exp2f(m_r - mn);
            l_r *= fsc;
            #pragma unroll
            for (int n=0;n<4;n++) o[n] *= fsc;
            m_r = mn;
        }
        float ps = 0.f;
        float p[8][4];
        #pragma unroll
        for (int kb=0;kb<8;kb++)
            #pragma unroll
            for (int r=0;r<4;r++) {
                float pe = exp2f(sc[kb][r] - m_r);
                p[kb][r] = pe;
                ps += pe;
            }
        ps += __shfl_xor(ps, 16);
        ps += __shfl_xor(ps, 32);
        l_r += ps;
        #pragma unroll
        for (int c=0;c<4;c++) {
            bf16x8 v;
            #pragma unroll
            for (int i=0;i<8;i++) v[i] = (bf16)p[c*2 + (i>>2)][i&3];
            pa[c] = v;
        }
    };

    int nIter = (qb + 2) >> 1;      // ceil((qb+1)/2); pairs give 17 total per block
    load_window(0); store_window(0); __syncthreads();

    for (int it = 0; it < nIter; it++) {
        int cur = it & 1;
        int kv0 = it * 128;
        bool last = (it + 1 == nIter);
        if (!last) load_window(kv0 + 128);
        bool doA = (kv0 <= qa*64 + 63);
        bool dgB = (kv0 + 127 > qb*64);
        bool dgA = (kv0 + 127 > qa*64);
        const bf16* ksb = &Ks[cur][0];
        const bf16* vsb = &Vs[cur][0];
        bf16x8 paB[4], paA[4];
        f32x4 scB[8];

        if (doA) {
            f32x4 scA[8];
            __builtin_amdgcn_s_setprio(1);
            #pragma unroll
            for (int kb=0;kb<8;kb++) {
                int row = kb*16 + lr;
                bf16x8 k0 = *(const bf16x8*)&ksb[row*64 + ((lg     ^ (row&7))*8)];
                bf16x8 k1 = *(const bf16x8*)&ksb[row*64 + (((4+lg) ^ (row&7))*8)];
                scB[kb] = MFMA16(k0, qfB[0], zero4());
                scB[kb] = MFMA16(k1, qfB[1], scB[kb]);
                scA[kb] = MFMA16(k0, qfA[0], zero4());
                scA[kb] = MFMA16(k1, qfA[1], scA[kb]);
            }
            __builtin_amdgcn_s_setprio(0);
            softmax(scB, mB, lsB, oB, paB, dgB, kv0, q0b + lr);
            softmax(scA, mA, lsA, oA, paA, dgA, kv0, q0a + lr);
            __builtin_amdgcn_s_setprio(1);
            #pragma unroll
            for (int c=0;c<4;c++)
                #pragma unroll
                for (int n=0;n<4;n++) {
                    int row = n*16 + lr;
                    bf16x8 vf = *(const bf16x8*)&vsb[row*128 + (((c*4+lg) ^ (row&7))*8)];
                    oB[n] = MFMA16(vf, paB[c], oB[n]);
                    oA[n] = MFMA16(vf, paA[c], oA[n]);
                }
            __builtin_amdgcn_s_setprio(0);
        } else {
            __builtin_amdgcn_s_setprio(1);
            #pragma unroll
            for (int kb=0;kb<8;kb++) {
                int row = kb*16 + lr;
                bf16x8 k0 = *(const bf16x8*)&ksb[row*64 + ((lg     ^ (row&7))*8)];
                bf16x8 k1 = *(const bf16x8*)&ksb[row*64 + (((4+lg) ^ (row&7))*8)];
                scB[kb] = MFMA16(k0, qfB[0], zero4());
                scB[kb] = MFMA16(k1, qfB[1], scB[kb]);
            }
            __builtin_amdgcn_s_setprio(0);
            softmax(scB, mB, lsB, oB, paB, dgB, kv0, q0b + lr);
            __builtin_amdgcn_s_setprio(1);
            #pragma unroll
            for (int c=0;c<4;c++)
                #pragma unroll
                for (int n=0;n<4;n++) {
                    int row = n*16 + lr;
                    bf16x8 vf = *(const bf16x8*)&vsb[row*128 + (((c*4+lg) ^ (row&7))*8)];
                    oB[n] = MFMA16(vf, paB[c], oB[n]);
                }
            __builtin_amdgcn_s_setprio(0);
        }
        if (!last) { store_window(cur^1); __syncthreads(); }
    }

    // epilogue: normalize, write [b,s,h,d] as bf16x4 chunks (lane owns q-row lr, d-slice lg*4)
    float invB = 1.0f / lsB;
    float invA = 1.0f / lsA;
    int qB = q0b + lr, qA = q0a + lr;
    #pragma unroll
    for (int n=0;n<4;n++) {
        bf16x4 o1, o2;
        #pragma unroll
        for (int r=0;r<4;r++) {
            o1[r] = (bf16)(oB[n][r] * invB);
            o2[r] = (bf16)(oA[n][r] * invA);
        }
        *(bf16x4*)&AO[((size_t)(b*NS + qB)*NH + h)*HD + n*16 + lg*4] = o1;
        *(bf16x4*)&AO[((size_t)(b*NS + qA)*NH + h)*HD + n*16 + lg*4] = o2;
    }
}

extern "C" void kernel_launch(void* const* d_in, const int* in_sizes, int n_in,
                              void* d_out, int out_size, void* d_ws, size_t ws_size,
                              hipStream_t stream) {
    const float* x     = (const float*)d_in[0];
    const float* w_in  = (const float*)d_in[1];
    const float* w_out = (const float*)d_in[2];
    float* out = (float*)d_out;

    char* p = (char*)d_ws;
    bf16* xb    = (bf16*)p; p += (size_t)BS*ND*2;          // 8 MB
    bf16* winb  = (bf16*)p; p += (size_t)D3*ND*2;          // 6 MB
    bf16* woutb = (bf16*)p; p += (size_t)ND*ND*2;          // 2 MB
    bf16* Qb    = (bf16*)p; p += (size_t)NB*NH*NS*HD*2;    // 8 MB
    bf16* Kb    = (bf16*)p; p += (size_t)NB*NH*NS*HD*2;    // 8 MB
    bf16* Vp    = (bf16*)p; p += (size_t)NB*NH*NS*HD*2;    // 8 MB  (V^T, k-permuted, [bh][d][s'])
    bf16* AO    = (bf16*)p; p += (size_t)BS*ND*2;          // 8 MB
    float* cosT = (float*)p; p += (size_t)NS*32*4;
    float* sinT = (float*)p; p += (size_t)NS*32*4;

    prep<<<(CVTN + NS*32)/256, 256, 0, stream>>>(x, w_in, w_out, xb, winb, woutb, cosT, sinT);
    gemm_bt<1><<<dim3(D3/128, BS/128), 256, 0, stream>>>(xb, winb, nullptr, Qb, Kb, Vp,
                                                         cosT, sinT, BS, D3, ND);
    attn_fwd<<<NB*NH*(NT/2), 256, 0, stream>>>(Qb, Kb, Vp, AO);
    gemm_bt<0><<<dim3(ND/128, BS/128), 256, 0, stream>>>(AO, woutb, out, nullptr, nullptr, nullptr,
                                                         nullptr, nullptr, BS, ND, ND);
}

// Round 5
// 116.463 us; speedup vs baseline: 2.1415x; 1.0811x over previous
//
#include <hip/hip_runtime.h>
#include <hip/hip_bf16.h>
#include <math.h>

// Problem constants
#define NB 2
#define NS 2048
#define ND 1024
#define NH 16
#define HD 64
#define BS (NB*NS)     // 4096 tokens
#define D3 (3*ND)      // 3072
#define NT (NS/64)     // 32 q-tiles of 64

typedef __bf16 bf16;
typedef __bf16 bf16x4 __attribute__((ext_vector_type(4)));
typedef __bf16 bf16x8 __attribute__((ext_vector_type(8)));
typedef float f32x4 __attribute__((ext_vector_type(4)));

#define MFMA16(a,b,c) __builtin_amdgcn_mfma_f32_16x16x32_bf16(a,b,c,0,0,0)

static __device__ inline f32x4 zero4() { f32x4 z; z[0]=0.f; z[1]=0.f; z[2]=0.f; z[3]=0.f; return z; }

// global -> LDS direct copy, 16B per lane; lds base must be wave-uniform.
__device__ __forceinline__ void gload_lds16(const bf16* g, bf16* l) {
    __builtin_amdgcn_global_load_lds(
        (__attribute__((address_space(1))) unsigned int*)g,
        (__attribute__((address_space(3))) unsigned int*)l, 16, 0, 0);
}

// ---------------- prep: f32->bf16 for x/w_in/w_out + RoPE tables, one launch ----------------
#define CVT1 (BS*ND/8)          // 524288
#define CVT2 (D3*ND/8)          // 393216
#define CVT3 (ND*ND/8)          // 131072
#define CVTN (CVT1+CVT2+CVT3)   // 1048576
__global__ __launch_bounds__(256) void prep(
    const float* __restrict__ x, const float* __restrict__ w_in, const float* __restrict__ w_out,
    bf16* __restrict__ xb, bf16* __restrict__ winb, bf16* __restrict__ woutb,
    float* __restrict__ cosT, float* __restrict__ sinT)
{
    int i = blockIdx.x * 256 + threadIdx.x;
    if (i < CVTN) {
        const float* in; bf16* out; int j;
        if (i < CVT1)            { in = x;     out = xb;    j = i; }
        else if (i < CVT1+CVT2)  { in = w_in;  out = winb;  j = i - CVT1; }
        else                     { in = w_out; out = woutb; j = i - CVT1 - CVT2; }
        const float4* p = (const float4*)in;
        float4 a = p[j*2], b = p[j*2+1];
        bf16x8 o;
        o[0]=(bf16)a.x; o[1]=(bf16)a.y; o[2]=(bf16)a.z; o[3]=(bf16)a.w;
        o[4]=(bf16)b.x; o[5]=(bf16)b.y; o[6]=(bf16)b.z; o[7]=(bf16)b.w;
        ((bf16x8*)out)[j] = o;
    } else {
        int k = i - CVTN;                      // [0, NS*32)
        int s = k >> 5, j = k & 31;
        float inv = __expf(-(float)j * (9.210340372f * 0.03125f));  // 10000^(-j/32)
        float ang = (float)s * inv;
        cosT[k] = cosf(ang);
        sinT[k] = sinf(ang);
    }
}

// ---------------- GEMM: C[m,n] = sum_k A[m,k]*B[n,k], bf16, BK=64, swizzled LDS ----------------
// Staging: global_load_lds (linear dest) + pre-swizzled SOURCE chunk; reads use same XOR (rule 21).
// EPI==0: f32 store. EPI==1: fused RoPE -> Q/K head-major [bh][s][d]; V^T k-permuted [bh][d][s'].
template<int EPI>
__global__ __launch_bounds__(256) void gemm_bt(
    const bf16* __restrict__ A, const bf16* __restrict__ Bm,
    float* __restrict__ C, bf16* __restrict__ Qb, bf16* __restrict__ Kb, bf16* __restrict__ Vt,
    const float* __restrict__ cosT, const float* __restrict__ sinT,
    int M, int N, int K)
{
    __shared__ bf16 As[128*64];
    __shared__ bf16 Bs[128*64];
    int t = threadIdx.x;
    int lane = t & 63, w = t >> 6;
    int wr = w >> 1, wc = w & 1;
    int lr = lane & 15, lg = lane >> 4;
    int m0 = blockIdx.y * 128, n0 = blockIdx.x * 128;

    // staging: wave w covers 32 rows of A and B; source chunk pre-swizzled by row&7
    int srow = lane >> 3;                 // 0..7
    int schunk = (lane & 7) ^ srow;       // XOR-swizzled source chunk
    const bf16* gA = &A [(size_t)(m0 + w*32 + srow)*K + schunk*8];
    const bf16* gB = &Bm[(size_t)(n0 + w*32 + srow)*K + schunk*8];
    bf16* lA = &As[w*2048];
    bf16* lB = &Bs[w*2048];

    f32x4 acc[4][4];
    for (int m=0;m<4;m++) for (int n=0;n<4;n++) acc[m][n] = zero4();

    for (int k0 = 0; k0 < K; k0 += 64) {
        #pragma unroll
        for (int i=0;i<4;i++) {
            gload_lds16(gA + (size_t)(i*8)*K + k0, lA + i*512);
            gload_lds16(gB + (size_t)(i*8)*K + k0, lB + i*512);
        }
        __syncthreads();
        #pragma unroll
        for (int ks=0;ks<2;ks++) {
            bf16x8 af[4], bfr[4];
            #pragma unroll
            for (int m=0;m<4;m++) {
                int row = wr*64 + m*16 + lr;
                af[m] = *(const bf16x8*)&As[row*64 + (((ks*4+lg) ^ (row&7))*8)];
            }
            #pragma unroll
            for (int n=0;n<4;n++) {
                int row = wc*64 + n*16 + lr;
                bfr[n] = *(const bf16x8*)&Bs[row*64 + (((ks*4+lg) ^ (row&7))*8)];
            }
            #pragma unroll
            for (int m=0;m<4;m++)
                #pragma unroll
                for (int n=0;n<4;n++)
                    acc[m][n] = MFMA16(af[m], bfr[n], acc[m][n]);
        }
        __syncthreads();
    }

    if (EPI == 0) {
        for (int m=0;m<4;m++) for (int n=0;n<4;n++) {
            int grow = m0 + wr*64 + m*16 + lg*4;
            int gcol = n0 + wc*64 + n*16 + lr;
            for (int r=0;r<4;r++)
                C[(size_t)(grow+r) * N + gcol] = acc[m][n][r];
        }
    } else {
        int which = n0 >> 10;   // block-uniform (128-col block never straddles a 1024 boundary)
        if (which == 2) {
            // V^T with within-64 k-permutation: col(t) = ((t>>5)&1)*32+((t>>2)&3)*8+((t>>4)&1)*4+(t&3)
            for (int m=0;m<4;m++) for (int n=0;n<4;n++) {
                int grow = m0 + wr*64 + m*16 + lg*4;
                int gcol = n0 + wc*64 + n*16 + lr;
                int h = (gcol & 1023) >> 6, d = gcol & 63;
                int b = grow >> 11, s0 = grow & (NS-1);
                int shi = s0 & ~63, j = s0 & 63;   // j % 4 == 0
                int kp = ((j>>5)&1)*32 + ((j>>2)&3)*8 + ((j>>4)&1)*4;
                bf16x4 pv;
                for (int r=0;r<4;r++) pv[r] = (bf16)acc[m][n][r];
                *(bf16x4*)&Vt[((size_t)((b*NH + h)*HD + d))*NS + shi + kp] = pv;
            }
        } else {
            // fused RoPE: pairs (d, d+32) = acc n and n+2, same lane
            const float qs = 0.125f * 1.44269504f;   // fold softmax scale + log2(e) into Q
            bf16* dst = (which == 0) ? Qb : Kb;
            for (int m=0;m<4;m++) {
                int grow = m0 + wr*64 + m*16 + lg*4;
                #pragma unroll
                for (int n=0;n<2;n++) {
                    int gcol = n0 + wc*64 + n*16 + lr;
                    int h = (gcol & 1023) >> 6, j = gcol & 63;   // j in [0,32)
                    #pragma unroll
                    for (int r=0;r<4;r++) {
                        int gm = grow + r;
                        int b = gm >> 11, s = gm & (NS-1);
                        float c  = cosT[(s<<5)+j];
                        float sn = sinT[(s<<5)+j];
                        float x1 = acc[m][n][r], x2 = acc[m][n+2][r];
                        float y1 = x1*c - x2*sn;
                        float y2 = x2*c + x1*sn;
                        if (which == 0) { y1 *= qs; y2 *= qs; }
                        size_t off = ((size_t)((b*NH + h)*NS + s))*HD;
                        dst[off + j]      = (bf16)y1;
                        dst[off + j + 32] = (bf16)y2;
                    }
                }
            }
        }
    }
}

// ---------------- causal flash attention: KVBLK=64, 1 q-tile/block, LPT order ----------------
// grid: 1024 blocks; wgid>>5 gives qt DESCENDING (heavy blocks dispatch first), bh = wgid&31.
__global__ __launch_bounds__(256, 4) void attn_fwd(
    const bf16* __restrict__ Qb, const bf16* __restrict__ Kb, const bf16* __restrict__ Vp,
    bf16* __restrict__ AO)
{
    __shared__ bf16 Ks[2][64*64];      // [buf][key][d], chunk-swizzled
    __shared__ bf16 Vs[2][64*64];      // [buf][d][k'],  chunk-swizzled
    int t = threadIdx.x;
    int lane = t & 63, w = t >> 6;
    int lr = lane & 15, lg = lane >> 4;
    int wgid = blockIdx.x;
    int qt = (NT-1) - (wgid >> 5);     // LPT: heaviest first
    int bh = wgid & 31;
    int b = bh >> 4, h = bh & 15;
    size_t base = (size_t)bh * NS * HD;
    int q0 = qt*64 + w*16;

    bf16x8 qf[2];
    #pragma unroll
    for (int c=0;c<2;c++)
        qf[c] = *(const bf16x8*)&Qb[base + (size_t)(q0+lr)*HD + c*32 + lg*8];

    float m_r = -__builtin_inff(), l_r = 0.f;
    f32x4 o[4];
    #pragma unroll
    for (int n=0;n<4;n++) o[n] = zero4();

    // staging addressing (reg-staged for swizzled writes): 32 rows x 8 chunks per pass, 2 passes
    int srow = t >> 3;                 // 0..31
    int sch  = t & 7;
    int sslot = sch ^ (srow & 7);
    bf16x8 kr[2], vr[2];

    auto load_window = [&](int kv0) {
        #pragma unroll
        for (int i=0;i<2;i++)
            kr[i] = *(const bf16x8*)&Kb[base + (size_t)(kv0 + i*32 + srow)*HD + sch*8];
        #pragma unroll
        for (int i=0;i<2;i++)
            vr[i] = *(const bf16x8*)&Vp[base + (size_t)(i*32 + srow)*NS + kv0 + sch*8];
    };
    auto store_window = [&](int buf) {
        #pragma unroll
        for (int i=0;i<2;i++)
            *(bf16x8*)&Ks[buf][(i*32 + srow)*64 + sslot*8] = kr[i];
        #pragma unroll
        for (int i=0;i<2;i++)
            *(bf16x8*)&Vs[buf][(i*32 + srow)*64 + sslot*8] = vr[i];
    };

    for (int kt = 0; kt <= qt; kt++) {
        if (kt == 0) { load_window(0); store_window(0); __syncthreads(); }
        int cur = kt & 1;
        int kv0 = kt*64;
        bool last = (kt == qt);
        if (!last) load_window(kv0 + 64);          // issue next-tile loads early (T14)

        const bf16* ksb = &Ks[cur][0];
        const bf16* vsb = &Vs[cur][0];

        // ---- S^T = K Q (log2 domain; Q pre-scaled) ----
        f32x4 sc[4];
        __builtin_amdgcn_s_setprio(1);
        #pragma unroll
        for (int kb=0;kb<4;kb++) {
            int row = kb*16 + lr;
            bf16x8 k0 = *(const bf16x8*)&ksb[row*64 + ((lg     ^ (row&7))*8)];
            bf16x8 k1 = *(const bf16x8*)&ksb[row*64 + (((4+lg) ^ (row&7))*8)];
            sc[kb] = MFMA16(k0, qf[0], zero4());
            sc[kb] = MFMA16(k1, qf[1], sc[kb]);
        }
        __builtin_amdgcn_s_setprio(0);

        if (last) {        // diagonal tile mask: k > q
            int qi = q0 + lr;
            #pragma unroll
            for (int kb=0;kb<4;kb++)
                #pragma unroll
                for (int r=0;r<4;r++)
                    if (kv0 + kb*16 + lg*4 + r > qi) sc[kb][r] = -__builtin_inff();
        }

        // ---- online softmax (lane owns q-row lr; 15 local + 2 shuffles) ----
        float tm = fmaxf(fmaxf(sc[0][0],sc[0][1]), fmaxf(sc[0][2],sc[0][3]));
        #pragma unroll
        for (int kb=1;kb<4;kb++)
            tm = fmaxf(tm, fmaxf(fmaxf(sc[kb][0],sc[kb][1]), fmaxf(sc[kb][2],sc[kb][3])));
        tm = fmaxf(tm, __shfl_xor(tm, 16));
        tm = fmaxf(tm, __shfl_xor(tm, 32));
        if (!__all(tm <= m_r + 8.0f)) {            // defer-max (T13)
            float mn = fmaxf(m_r, tm);
            float fsc = exp2f(m_r - mn);
            l_r *= fsc;
            #pragma unroll
            for (int n=0;n<4;n++) o[n] *= fsc;
            m_r = mn;
        }
        float p[4][4];
        float ps = 0.f;
        #pragma unroll
        for (int kb=0;kb<4;kb++)
            #pragma unroll
            for (int r=0;r<4;r++) {
                float pe = exp2f(sc[kb][r] - m_r);
                p[kb][r] = pe;
                ps += pe;
            }
        ps += __shfl_xor(ps, 16);
        ps += __shfl_xor(ps, 32);
        l_r += ps;

        // pack P to bf16 in the k-slot order matching the permuted V layout
        bf16x8 pa[2];
        #pragma unroll
        for (int c=0;c<2;c++) {
            bf16x8 v;
            #pragma unroll
            for (int i=0;i<8;i++) v[i] = (bf16)p[c*2 + (i>>2)][i&3];
            pa[c] = v;
        }

        // ---- O += P V ----
        __builtin_amdgcn_s_setprio(1);
        #pragma unroll
        for (int c=0;c<2;c++)
            #pragma unroll
            for (int n=0;n<4;n++) {
                int row = n*16 + lr;
                bf16x8 vf = *(const bf16x8*)&vsb[row*64 + (((c*4+lg) ^ (row&7))*8)];
                o[n] = MFMA16(vf, pa[c], o[n]);
            }
        __builtin_amdgcn_s_setprio(0);

        if (!last) { store_window(cur^1); __syncthreads(); }
    }

    // epilogue: normalize, write [b,s,h,d] as bf16x4 chunks (lane owns q-row lr, d-slice lg*4)
    float inv = 1.0f / l_r;
    int q = q0 + lr;
    #pragma unroll
    for (int n=0;n<4;n++) {
        bf16x4 ov;
        #pragma unroll
        for (int r=0;r<4;r++) ov[r] = (bf16)(o[n][r] * inv);
        *(bf16x4*)&AO[((size_t)(b*NS + q)*NH + h)*HD + n*16 + lg*4] = ov;
    }
}

extern "C" void kernel_launch(void* const* d_in, const int* in_sizes, int n_in,
                              void* d_out, int out_size, void* d_ws, size_t ws_size,
                              hipStream_t stream) {
    const float* x     = (const float*)d_in[0];
    const float* w_in  = (const float*)d_in[1];
    const float* w_out = (const float*)d_in[2];
    float* out = (float*)d_out;

    char* p = (char*)d_ws;
    bf16* xb    = (bf16*)p; p += (size_t)BS*ND*2;          // 8 MB
    bf16* winb  = (bf16*)p; p += (size_t)D3*ND*2;          // 6 MB
    bf16* woutb = (bf16*)p; p += (size_t)ND*ND*2;          // 2 MB
    bf16* Qb    = (bf16*)p; p += (size_t)NB*NH*NS*HD*2;    // 8 MB
    bf16* Kb    = (bf16*)p; p += (size_t)NB*NH*NS*HD*2;    // 8 MB
    bf16* Vp    = (bf16*)p; p += (size_t)NB*NH*NS*HD*2;    // 8 MB  (V^T, k-permuted, [bh][d][s'])
    bf16* AO    = (bf16*)p; p += (size_t)BS*ND*2;          // 8 MB
    float* cosT = (float*)p; p += (size_t)NS*32*4;
    float* sinT = (float*)p; p += (size_t)NS*32*4;

    prep<<<(CVTN + NS*32)/256, 256, 0, stream>>>(x, w_in, w_out, xb, winb, woutb, cosT, sinT);
    gemm_bt<1><<<dim3(D3/128, BS/128), 256, 0, stream>>>(xb, winb, nullptr, Qb, Kb, Vp,
                                                         cosT, sinT, BS, D3, ND);
    attn_fwd<<<NB*NH*NT, 256, 0, stream>>>(Qb, Kb, Vp, AO);
    gemm_bt<0><<<dim3(ND/128, BS/128), 256, 0, stream>>>(AO, woutb, out, nullptr, nullptr, nullptr,
                                                         nullptr, nullptr, BS, ND, ND);
}

// Round 6
// 102.535 us; speedup vs baseline: 2.4324x; 1.1358x over previous
//
#include <hip/hip_runtime.h>
#include <hip/hip_bf16.h>
#include <math.h>

// Problem constants
#define NB 2
#define NS 2048
#define ND 1024
#define NH 16
#define HD 64
#define BS (NB*NS)     // 4096 tokens
#define D3 (3*ND)      // 3072
#define NT (NS/64)     // 32 q-tiles of 64

typedef __bf16 bf16;
typedef __bf16 bf16x4 __attribute__((ext_vector_type(4)));
typedef __bf16 bf16x8 __attribute__((ext_vector_type(8)));
typedef float f32x4 __attribute__((ext_vector_type(4)));

#define MFMA16(a,b,c) __builtin_amdgcn_mfma_f32_16x16x32_bf16(a,b,c,0,0,0)

static __device__ inline f32x4 zero4() { f32x4 z; z[0]=0.f; z[1]=0.f; z[2]=0.f; z[3]=0.f; return z; }

// global -> LDS direct copy, 16B per lane; lds base must be wave-uniform.
__device__ __forceinline__ void gload_lds16(const bf16* g, bf16* l) {
    __builtin_amdgcn_global_load_lds(
        (__attribute__((address_space(1))) unsigned int*)g,
        (__attribute__((address_space(3))) unsigned int*)l, 16, 0, 0);
}

// ---------------- prep: f32->bf16 for x/w_in/w_out + RoPE tables, one launch ----------------
#define CVT1 (BS*ND/8)          // 524288
#define CVT2 (D3*ND/8)          // 393216
#define CVT3 (ND*ND/8)          // 131072
#define CVTN (CVT1+CVT2+CVT3)   // 1048576
__global__ __launch_bounds__(256) void prep(
    const float* __restrict__ x, const float* __restrict__ w_in, const float* __restrict__ w_out,
    bf16* __restrict__ xb, bf16* __restrict__ winb, bf16* __restrict__ woutb,
    float* __restrict__ cosT, float* __restrict__ sinT)
{
    int i = blockIdx.x * 256 + threadIdx.x;
    if (i < CVTN) {
        const float* in; bf16* out; int j;
        if (i < CVT1)            { in = x;     out = xb;    j = i; }
        else if (i < CVT1+CVT2)  { in = w_in;  out = winb;  j = i - CVT1; }
        else                     { in = w_out; out = woutb; j = i - CVT1 - CVT2; }
        const float4* p = (const float4*)in;
        float4 a = p[j*2], b = p[j*2+1];
        bf16x8 o;
        o[0]=(bf16)a.x; o[1]=(bf16)a.y; o[2]=(bf16)a.z; o[3]=(bf16)a.w;
        o[4]=(bf16)b.x; o[5]=(bf16)b.y; o[6]=(bf16)b.z; o[7]=(bf16)b.w;
        ((bf16x8*)out)[j] = o;
    } else {
        int k = i - CVTN;                      // [0, NS*32)
        int s = k >> 5, j = k & 31;
        float inv = __expf(-(float)j * (9.210340372f * 0.03125f));  // 10000^(-j/32)
        float ang = (float)s * inv;
        cosT[k] = cosf(ang);
        sinT[k] = sinf(ang);
    }
}

// ---------------- GEMM: C[m,n] = sum_k A[m,k]*B[n,k], bf16, BK=64, swizzled LDS ----------------
// Double-buffered LDS + counted vmcnt (never drains to 0 in the main loop).
// Staging: global_load_lds (linear dest) + pre-swizzled SOURCE chunk; reads use same XOR (rule 21).
// EPI==0: f32 store. EPI==1: fused RoPE -> Q/K head-major [bh][s][d]; V^T k-permuted [bh][d][s'].
template<int EPI>
__global__ __launch_bounds__(256) void gemm_bt(
    const bf16* __restrict__ A, const bf16* __restrict__ Bm,
    float* __restrict__ C, bf16* __restrict__ Qb, bf16* __restrict__ Kb, bf16* __restrict__ Vt,
    const float* __restrict__ cosT, const float* __restrict__ sinT,
    int M, int N, int K)
{
    __shared__ bf16 As[2][128*64];
    __shared__ bf16 Bs[2][128*64];
    int t = threadIdx.x;
    int lane = t & 63, w = t >> 6;
    int wr = w >> 1, wc = w & 1;
    int lr = lane & 15, lg = lane >> 4;
    int m0 = blockIdx.y * 128, n0 = blockIdx.x * 128;

    // staging: wave w covers 32 rows of A and B; source chunk pre-swizzled by row&7
    int srow = lane >> 3;                 // 0..7
    int schunk = (lane & 7) ^ srow;       // XOR-swizzled source chunk
    const bf16* gA = &A [(size_t)(m0 + w*32 + srow)*K + schunk*8];
    const bf16* gB = &Bm[(size_t)(n0 + w*32 + srow)*K + schunk*8];

    // issue one K-tile's staging (8 gload_lds per wave, 1KB each)
    auto stage = [&](int kt) {
        int buf = kt & 1;
        bf16* lA = &As[buf][w*2048];
        bf16* lB = &Bs[buf][w*2048];
        int k0 = kt * 64;
        #pragma unroll
        for (int i=0;i<4;i++) {
            gload_lds16(gA + (size_t)(i*8)*K + k0, lA + i*512);
            gload_lds16(gB + (size_t)(i*8)*K + k0, lB + i*512);
        }
    };

    f32x4 acc[4][4];
    for (int m=0;m<4;m++) for (int n=0;n<4;n++) acc[m][n] = zero4();

    int nt = K >> 6;                       // K-tiles (>= 2 here)
    stage(0);
    stage(1);                              // outstanding: 16 loads

    for (int kt = 0; kt < nt; kt++) {
        int cur = kt & 1;
        // wait for tile kt only (8 oldest); keep tile kt+1's 8 loads in flight
        if (kt < nt-1) asm volatile("s_waitcnt vmcnt(8)" ::: "memory");
        else           asm volatile("s_waitcnt vmcnt(0)" ::: "memory");
        __builtin_amdgcn_s_barrier();                  // tile kt visible to all waves
        __builtin_amdgcn_sched_barrier(0);

        bf16x8 af[2][4], bfr[2][4];
        #pragma unroll
        for (int ks=0;ks<2;ks++) {
            #pragma unroll
            for (int m=0;m<4;m++) {
                int row = wr*64 + m*16 + lr;
                af[ks][m] = *(const bf16x8*)&As[cur][row*64 + (((ks*4+lg) ^ (row&7))*8)];
            }
            #pragma unroll
            for (int n=0;n<4;n++) {
                int row = wc*64 + n*16 + lr;
                bfr[ks][n] = *(const bf16x8*)&Bs[cur][row*64 + (((ks*4+lg) ^ (row&7))*8)];
            }
        }
        asm volatile("s_waitcnt lgkmcnt(0)" ::: "memory");
        __builtin_amdgcn_sched_barrier(0);             // rule 18: pin MFMA after lgkmcnt
        __builtin_amdgcn_s_barrier();                  // all waves done reading buf cur
        __builtin_amdgcn_sched_barrier(0);

        if (kt + 2 < nt) stage(kt + 2);                // overwrite buf cur for tile kt+2

        __builtin_amdgcn_s_setprio(1);
        #pragma unroll
        for (int ks=0;ks<2;ks++)
            #pragma unroll
            for (int m=0;m<4;m++)
                #pragma unroll
                for (int n=0;n<4;n++)
                    acc[m][n] = MFMA16(af[ks][m], bfr[ks][n], acc[m][n]);
        __builtin_amdgcn_s_setprio(0);
    }

    if (EPI == 0) {
        for (int m=0;m<4;m++) for (int n=0;n<4;n++) {
            int grow = m0 + wr*64 + m*16 + lg*4;
            int gcol = n0 + wc*64 + n*16 + lr;
            for (int r=0;r<4;r++)
                C[(size_t)(grow+r) * N + gcol] = acc[m][n][r];
        }
    } else {
        int which = n0 >> 10;   // block-uniform (128-col block never straddles a 1024 boundary)
        if (which == 2) {
            // V^T with within-64 k-permutation: col(t) = ((t>>5)&1)*32+((t>>2)&3)*8+((t>>4)&1)*4+(t&3)
            for (int m=0;m<4;m++) for (int n=0;n<4;n++) {
                int grow = m0 + wr*64 + m*16 + lg*4;
                int gcol = n0 + wc*64 + n*16 + lr;
                int h = (gcol & 1023) >> 6, d = gcol & 63;
                int b = grow >> 11, s0 = grow & (NS-1);
                int shi = s0 & ~63, j = s0 & 63;   // j % 4 == 0
                int kp = ((j>>5)&1)*32 + ((j>>2)&3)*8 + ((j>>4)&1)*4;
                bf16x4 pv;
                for (int r=0;r<4;r++) pv[r] = (bf16)acc[m][n][r];
                *(bf16x4*)&Vt[((size_t)((b*NH + h)*HD + d))*NS + shi + kp] = pv;
            }
        } else {
            // fused RoPE: pairs (d, d+32) = acc n and n+2, same lane
            const float qs = 0.125f * 1.44269504f;   // fold softmax scale + log2(e) into Q
            bf16* dst = (which == 0) ? Qb : Kb;
            for (int m=0;m<4;m++) {
                int grow = m0 + wr*64 + m*16 + lg*4;
                #pragma unroll
                for (int n=0;n<2;n++) {
                    int gcol = n0 + wc*64 + n*16 + lr;
                    int h = (gcol & 1023) >> 6, j = gcol & 63;   // j in [0,32)
                    #pragma unroll
                    for (int r=0;r<4;r++) {
                        int gm = grow + r;
                        int b = gm >> 11, s = gm & (NS-1);
                        float c  = cosT[(s<<5)+j];
                        float sn = sinT[(s<<5)+j];
                        float x1 = acc[m][n][r], x2 = acc[m][n+2][r];
                        float y1 = x1*c - x2*sn;
                        float y2 = x2*c + x1*sn;
                        if (which == 0) { y1 *= qs; y2 *= qs; }
                        size_t off = ((size_t)((b*NH + h)*NS + s))*HD;
                        dst[off + j]      = (bf16)y1;
                        dst[off + j + 32] = (bf16)y2;
                    }
                }
            }
        }
    }
}

// ---------------- causal flash attention: KVBLK=64, 1 q-tile/block, LPT order ----------------
// grid: 1024 blocks; wgid>>5 gives qt DESCENDING (heavy blocks dispatch first), bh = wgid&31.
__global__ __launch_bounds__(256, 4) void attn_fwd(
    const bf16* __restrict__ Qb, const bf16* __restrict__ Kb, const bf16* __restrict__ Vp,
    bf16* __restrict__ AO)
{
    __shared__ bf16 Ks[2][64*64];      // [buf][key][d], chunk-swizzled
    __shared__ bf16 Vs[2][64*64];      // [buf][d][k'],  chunk-swizzled
    int t = threadIdx.x;
    int lane = t & 63, w = t >> 6;
    int lr = lane & 15, lg = lane >> 4;
    int wgid = blockIdx.x;
    int qt = (NT-1) - (wgid >> 5);     // LPT: heaviest first
    int bh = wgid & 31;
    int b = bh >> 4, h = bh & 15;
    size_t base = (size_t)bh * NS * HD;
    int q0 = qt*64 + w*16;

    bf16x8 qf[2];
    #pragma unroll
    for (int c=0;c<2;c++)
        qf[c] = *(const bf16x8*)&Qb[base + (size_t)(q0+lr)*HD + c*32 + lg*8];

    float m_r = -__builtin_inff(), l_r = 0.f;
    f32x4 o[4];
    #pragma unroll
    for (int n=0;n<4;n++) o[n] = zero4();

    // staging addressing (reg-staged for swizzled writes): 32 rows x 8 chunks per pass, 2 passes
    int srow = t >> 3;                 // 0..31
    int sch  = t & 7;
    int sslot = sch ^ (srow & 7);
    bf16x8 kr[2], vr[2];

    auto load_window = [&](int kv0) {
        #pragma unroll
        for (int i=0;i<2;i++)
            kr[i] = *(const bf16x8*)&Kb[base + (size_t)(kv0 + i*32 + srow)*HD + sch*8];
        #pragma unroll
        for (int i=0;i<2;i++)
            vr[i] = *(const bf16x8*)&Vp[base + (size_t)(i*32 + srow)*NS + kv0 + sch*8];
    };
    auto store_window = [&](int buf) {
        #pragma unroll
        for (int i=0;i<2;i++)
            *(bf16x8*)&Ks[buf][(i*32 + srow)*64 + sslot*8] = kr[i];
        #pragma unroll
        for (int i=0;i<2;i++)
            *(bf16x8*)&Vs[buf][(i*32 + srow)*64 + sslot*8] = vr[i];
    };

    for (int kt = 0; kt <= qt; kt++) {
        if (kt == 0) { load_window(0); store_window(0); __syncthreads(); }
        int cur = kt & 1;
        int kv0 = kt*64;
        bool last = (kt == qt);
        if (!last) load_window(kv0 + 64);          // issue next-tile loads early (T14)

        const bf16* ksb = &Ks[cur][0];
        const bf16* vsb = &Vs[cur][0];

        // ---- S^T = K Q (log2 domain; Q pre-scaled) ----
        f32x4 sc[4];
        __builtin_amdgcn_s_setprio(1);
        #pragma unroll
        for (int kb=0;kb<4;kb++) {
            int row = kb*16 + lr;
            bf16x8 k0 = *(const bf16x8*)&ksb[row*64 + ((lg     ^ (row&7))*8)];
            bf16x8 k1 = *(const bf16x8*)&ksb[row*64 + (((4+lg) ^ (row&7))*8)];
            sc[kb] = MFMA16(k0, qf[0], zero4());
            sc[kb] = MFMA16(k1, qf[1], sc[kb]);
        }
        __builtin_amdgcn_s_setprio(0);

        if (last) {        // diagonal tile mask: k > q
            int qi = q0 + lr;
            #pragma unroll
            for (int kb=0;kb<4;kb++)
                #pragma unroll
                for (int r=0;r<4;r++)
                    if (kv0 + kb*16 + lg*4 + r > qi) sc[kb][r] = -__builtin_inff();
        }

        // ---- online softmax (lane owns q-row lr; 15 local + 2 shuffles) ----
        float tm = fmaxf(fmaxf(sc[0][0],sc[0][1]), fmaxf(sc[0][2],sc[0][3]));
        #pragma unroll
        for (int kb=1;kb<4;kb++)
            tm = fmaxf(tm, fmaxf(fmaxf(sc[kb][0],sc[kb][1]), fmaxf(sc[kb][2],sc[kb][3])));
        tm = fmaxf(tm, __shfl_xor(tm, 16));
        tm = fmaxf(tm, __shfl_xor(tm, 32));
        if (!__all(tm <= m_r + 8.0f)) {            // defer-max (T13)
            float mn = fmaxf(m_r, tm);
            float fsc = exp2f(m_r - mn);
            l_r *= fsc;
            #pragma unroll
            for (int n=0;n<4;n++) o[n] *= fsc;
            m_r = mn;
        }
        float p[4][4];
        float ps = 0.f;
        #pragma unroll
        for (int kb=0;kb<4;kb++)
            #pragma unroll
            for (int r=0;r<4;r++) {
                float pe = exp2f(sc[kb][r] - m_r);
                p[kb][r] = pe;
                ps += pe;
            }
        ps += __shfl_xor(ps, 16);
        ps += __shfl_xor(ps, 32);
        l_r += ps;

        // pack P to bf16 in the k-slot order matching the permuted V layout
        bf16x8 pa[2];
        #pragma unroll
        for (int c=0;c<2;c++) {
            bf16x8 v;
            #pragma unroll
            for (int i=0;i<8;i++) v[i] = (bf16)p[c*2 + (i>>2)][i&3];
            pa[c] = v;
        }

        // ---- O += P V ----
        __builtin_amdgcn_s_setprio(1);
        #pragma unroll
        for (int c=0;c<2;c++)
            #pragma unroll
            for (int n=0;n<4;n++) {
                int row = n*16 + lr;
                bf16x8 vf = *(const bf16x8*)&vsb[row*64 + (((c*4+lg) ^ (row&7))*8)];
                o[n] = MFMA16(vf, pa[c], o[n]);
            }
        __builtin_amdgcn_s_setprio(0);

        if (!last) { store_window(cur^1); __syncthreads(); }
    }

    // epilogue: normalize, write [b,s,h,d] as bf16x4 chunks (lane owns q-row lr, d-slice lg*4)
    float inv = 1.0f / l_r;
    int q = q0 + lr;
    #pragma unroll
    for (int n=0;n<4;n++) {
        bf16x4 ov;
        #pragma unroll
        for (int r=0;r<4;r++) ov[r] = (bf16)(o[n][r] * inv);
        *(bf16x4*)&AO[((size_t)(b*NS + q)*NH + h)*HD + n*16 + lg*4] = ov;
    }
}

extern "C" void kernel_launch(void* const* d_in, const int* in_sizes, int n_in,
                              void* d_out, int out_size, void* d_ws, size_t ws_size,
                              hipStream_t stream) {
    const float* x     = (const float*)d_in[0];
    const float* w_in  = (const float*)d_in[1];
    const float* w_out = (const float*)d_in[2];
    float* out = (float*)d_out;

    char* p = (char*)d_ws;
    bf16* xb    = (bf16*)p; p += (size_t)BS*ND*2;          // 8 MB
    bf16* winb  = (bf16*)p; p += (size_t)D3*ND*2;          // 6 MB
    bf16* woutb = (bf16*)p; p += (size_t)ND*ND*2;          // 2 MB
    bf16* Qb    = (bf16*)p; p += (size_t)NB*NH*NS*HD*2;    // 8 MB
    bf16* Kb    = (bf16*)p; p += (size_t)NB*NH*NS*HD*2;    // 8 MB
    bf16* Vp    = (bf16*)p; p += (size_t)NB*NH*NS*HD*2;    // 8 MB  (V^T, k-permuted, [bh][d][s'])
    bf16* AO    = (bf16*)p; p += (size_t)BS*ND*2;          // 8 MB
    float* cosT = (float*)p; p += (size_t)NS*32*4;
    float* sinT = (float*)p; p += (size_t)NS*32*4;

    prep<<<(CVTN + NS*32)/256, 256, 0, stream>>>(x, w_in, w_out, xb, winb, woutb, cosT, sinT);
    gemm_bt<1><<<dim3(D3/128, BS/128), 256, 0, stream>>>(xb, winb, nullptr, Qb, Kb, Vp,
                                                         cosT, sinT, BS, D3, ND);
    attn_fwd<<<NB*NH*NT, 256, 0, stream>>>(Qb, Kb, Vp, AO);
    gemm_bt<0><<<dim3(ND/128, BS/128), 256, 0, stream>>>(AO, woutb, out, nullptr, nullptr, nullptr,
                                                         nullptr, nullptr, BS, ND, ND);
}